// Round 1
// baseline (3998.772 us; speedup 1.0000x reference)
//
#include <hip/hip_runtime.h>
#include <math.h>

// B=4, T=1024, C=2048, H=16, D=128, c8=256, N=B*T=4096
#define NROWS 4096
#define CDIM  2048

// Octonion sign table (Cayley-Dickson, verified against the reference recursion).
// WIDX[i][j] == i ^ j, so only signs needed.
__device__ __constant__ float SIGNS_c[64] = {
  1,  1,  1,  1,  1,  1,  1,  1,
  1, -1,  1, -1,  1, -1, -1,  1,
  1, -1, -1,  1,  1,  1, -1, -1,
  1,  1, -1, -1,  1, -1,  1, -1,
  1, -1, -1, -1, -1,  1,  1,  1,
  1,  1, -1,  1, -1, -1, -1,  1,
  1,  1,  1, -1, -1,  1, -1, -1,
  1, -1,  1,  1, -1, -1,  1, -1
};

// ---- per-matrix mean(|W|) in f64 (quantization boundary is precision-sensitive) ----
__global__ void scale_kernel(const float* __restrict__ W, double* __restrict__ s8) {
  int m = blockIdx.x;              // 0..7
  const float* w = W + (m << 16);  // 256*256 = 65536 elements
  double acc = 0.0;
  for (int i = threadIdx.x; i < 65536; i += 256) acc += (double)fabsf(w[i]);
  __shared__ double red[256];
  red[threadIdx.x] = acc;
  __syncthreads();
  for (int s = 128; s > 0; s >>= 1) {
    if (threadIdx.x < s) red[threadIdx.x] += red[threadIdx.x + s];
    __syncthreads();
  }
  if (threadIdx.x == 0) s8[m] = red[0] / 65536.0 + 1e-8;
}

// ---- expand octonion weight (8,256,256) -> dense 2048x2048, ternary-quantized ----
// M[row=j*256+c][col=i*256+d] = SIGNS[i][j] * q(W[i^j][c][d])
__global__ void build_oct_kernel(const float* __restrict__ W,
                                 const double* __restrict__ s8,
                                 float* __restrict__ M) {
  int idx = blockIdx.x * 256 + threadIdx.x;
  int col = idx & 2047, row = idx >> 11;
  int i = col >> 8, d = col & 255;
  int j = row >> 8, c = row & 255;
  int m = i ^ j;
  double s = s8[m];
  double w = (double)W[(m << 16) + (c << 8) + d];
  double q = rint(w / s);
  q = fmin(fmax(q, -1.0), 1.0);
  M[idx] = SIGNS_c[i * 8 + j] * (float)(q * s);
}

// ---- mixer: (8,128,128) + beta(128) -> block-diagonal 2048x2048 (2 groups of 8 heads) ----
__global__ void build_mix_kernel(const float* __restrict__ Wm,
                                 const float* __restrict__ beta,
                                 float* __restrict__ M) {
  int idx = blockIdx.x * 256 + threadIdx.x;
  int col = idx & 2047, row = idx >> 11;
  int g = row >> 10, gc = col >> 10;
  float v = 0.f;
  if (g == gc) {
    int j = (row >> 7) & 7, d = row & 127;
    int i = (col >> 7) & 7, e = col & 127;
    v = SIGNS_c[i * 8 + j] * Wm[((i ^ j) << 14) + (d << 7) + e] * beta[e];
  }
  M[idx] = v;
}

// ---- f32 GEMM: C[4096x2048] = A[4096x2048] @ B[2048x2048] ----
// 128x128 tile, BK=16, 256 threads, 8x8 per thread.
#define BKK 16
__global__ __launch_bounds__(256)
void gemm_f32(const float* __restrict__ A, const float* __restrict__ Bm,
              float* __restrict__ Cc) {
  __shared__ float As[BKK][132];  // transposed A tile (k-major), +4 pad
  __shared__ float Bs[BKK][128];
  int tid = threadIdx.x;
  int bn = blockIdx.x * 128;
  int bm = blockIdx.y * 128;
  int tm = (tid >> 4) * 8;
  int tn = (tid & 15) * 8;
  float acc[8][8] = {};
  for (int k0 = 0; k0 < CDIM; k0 += BKK) {
    // A tile: 128 rows x 16 k, float4 along k, store transposed
    #pragma unroll
    for (int l = 0; l < 2; ++l) {
      int e = tid + l * 256;           // 0..511 float4 units
      int m = e >> 2, k4 = (e & 3) * 4;
      float4 v = *(const float4*)&A[(size_t)(bm + m) * CDIM + k0 + k4];
      As[k4 + 0][m] = v.x; As[k4 + 1][m] = v.y;
      As[k4 + 2][m] = v.z; As[k4 + 3][m] = v.w;
    }
    // B tile: 16 k x 128 n, float4 along n
    #pragma unroll
    for (int l = 0; l < 2; ++l) {
      int e = tid + l * 256;           // 0..511 float4 units
      int kk = e >> 5, n4 = (e & 31) * 4;
      *(float4*)&Bs[kk][n4] = *(const float4*)&Bm[(size_t)(k0 + kk) * CDIM + bn + n4];
    }
    __syncthreads();
    #pragma unroll
    for (int kk = 0; kk < BKK; ++kk) {
      float4 a0 = *(const float4*)&As[kk][tm];
      float4 a1 = *(const float4*)&As[kk][tm + 4];
      float4 b0 = *(const float4*)&Bs[kk][tn];
      float4 b1 = *(const float4*)&Bs[kk][tn + 4];
      float a[8] = {a0.x, a0.y, a0.z, a0.w, a1.x, a1.y, a1.z, a1.w};
      float b[8] = {b0.x, b0.y, b0.z, b0.w, b1.x, b1.y, b1.z, b1.w};
      #pragma unroll
      for (int i = 0; i < 8; ++i)
        #pragma unroll
        for (int j = 0; j < 8; ++j) acc[i][j] += a[i] * b[j];
    }
    __syncthreads();
  }
  #pragma unroll
  for (int i = 0; i < 8; ++i) {
    size_t r = (size_t)(bm + tm + i) * CDIM + bn + tn;
    *(float4*)&Cc[r]     = make_float4(acc[i][0], acc[i][1], acc[i][2], acc[i][3]);
    *(float4*)&Cc[r + 4] = make_float4(acc[i][4], acc[i][5], acc[i][6], acc[i][7]);
  }
}

// ---- RoPE on Q and K in place; layout (B*T, H*D), pairs interleaved ----
__global__ void rope_kernel(float* __restrict__ Q, float* __restrict__ K,
                            const float* __restrict__ fc, const float* __restrict__ fs) {
  int idx = blockIdx.x * 256 + threadIdx.x;  // over N*H*64 = 4194304
  int p = idx & 63;
  int h = (idx >> 6) & 15;
  int n = idx >> 10;
  int t = n & 1023;
  float c = fc[t * 64 + p], s = fs[t * 64 + p];
  float2* q2 = (float2*)(Q + (size_t)n * CDIM + h * 128) + p;
  float2 v = *q2;
  *q2 = make_float2(v.x * c - v.y * s, v.x * s + v.y * c);
  float2* k2 = (float2*)(K + (size_t)n * CDIM + h * 128) + p;
  float2 w = *k2;
  *k2 = make_float2(w.x * c - w.y * s, w.x * s + w.y * c);
}

// ---- causal flash attention, f32 ----
// grid (32 qtiles, 64 bh), block 256 = 4 waves. 32 q-rows/block, 8 lanes per row,
// each lane owns a 16-float d-slice. O written in place (own rows only).
__global__ __launch_bounds__(256)
void attn_kernel(const float* __restrict__ Q, const float* __restrict__ K,
                 const float* __restrict__ V, float* __restrict__ O) {
  __shared__ float Ks[32][128];
  __shared__ float Vs[32][128];
  int tid = threadIdx.x;
  int qt = blockIdx.x;
  int bh = blockIdx.y;
  int b = bh >> 4, h = bh & 15;
  int row = tid >> 3;   // 0..31
  int dg = tid & 7;     // d-slice: dg*16 .. dg*16+15
  int qglob = qt * 32 + row;
  const float* qptr = Q + ((size_t)(b * 1024 + qglob)) * CDIM + h * 128 + dg * 16;
  float q[16], o[16];
  #pragma unroll
  for (int i = 0; i < 4; ++i) {
    float4 v = *(const float4*)(qptr + i * 4);
    q[i * 4] = v.x; q[i * 4 + 1] = v.y; q[i * 4 + 2] = v.z; q[i * 4 + 3] = v.w;
  }
  #pragma unroll
  for (int i = 0; i < 16; ++i) o[i] = 0.f;
  float mrun = -INFINITY, lrun = 0.f;
  const float scale = 0.08838834764831845f;  // 1/sqrt(128)

  for (int kt = 0; kt <= qt; ++kt) {
    int k0 = kt * 32;
    __syncthreads();  // protect previous tile reads
    #pragma unroll
    for (int l = 0; l < 4; ++l) {
      int e = tid + l * 256;           // 0..1023 float4 units
      int kr = e >> 5, d4 = (e & 31) * 4;
      size_t gofs = ((size_t)(b * 1024 + k0 + kr)) * CDIM + h * 128 + d4;
      *(float4*)&Ks[kr][d4] = *(const float4*)&K[gofs];
      *(float4*)&Vs[kr][d4] = *(const float4*)&V[gofs];
    }
    __syncthreads();

    float s[32];
    #pragma unroll
    for (int kk = 0; kk < 32; ++kk) {
      float partial = 0.f;
      const float* kro = &Ks[kk][dg * 16];
      #pragma unroll
      for (int i = 0; i < 16; ++i) partial += q[i] * kro[i];
      partial += __shfl_xor(partial, 1, 64);
      partial += __shfl_xor(partial, 2, 64);
      partial += __shfl_xor(partial, 4, 64);
      s[kk] = (k0 + kk <= qglob) ? partial * scale : -INFINITY;
    }
    float tmax = s[0];
    #pragma unroll
    for (int kk = 1; kk < 32; ++kk) tmax = fmaxf(tmax, s[kk]);
    float mnew = fmaxf(mrun, tmax);
    float factor = __expf(mrun - mnew);   // mrun=-inf first tile -> 0
    lrun *= factor;
    #pragma unroll
    for (int i = 0; i < 16; ++i) o[i] *= factor;
    #pragma unroll
    for (int kk = 0; kk < 32; ++kk) {
      float p = __expf(s[kk] - mnew);     // masked: exp(-inf)=0
      lrun += p;
      const float* vro = &Vs[kk][dg * 16];
      #pragma unroll
      for (int i = 0; i < 16; ++i) o[i] += p * vro[i];
    }
    mrun = mnew;
  }
  float inv = 1.f / lrun;
  float* optr = O + ((size_t)(b * 1024 + qglob)) * CDIM + h * 128 + dg * 16;
  #pragma unroll
  for (int i = 0; i < 4; ++i) {
    *(float4*)(optr + i * 4) = make_float4(o[i * 4] * inv, o[i * 4 + 1] * inv,
                                           o[i * 4 + 2] * inv, o[i * 4 + 3] * inv);
  }
}

extern "C" void kernel_launch(void* const* d_in, const int* in_sizes, int n_in,
                              void* d_out, int out_size, void* d_ws, size_t ws_size,
                              hipStream_t stream) {
  const float* x    = (const float*)d_in[0];
  const float* fc   = (const float*)d_in[1];
  const float* fs   = (const float*)d_in[2];
  const float* wq   = (const float*)d_in[3];
  const float* wk   = (const float*)d_in[4];
  const float* wv   = (const float*)d_in[5];
  const float* wo   = (const float*)d_in[6];
  const float* wm   = (const float*)d_in[7];
  const float* beta = (const float*)d_in[8];
  float* out = (float*)d_out;
  float* ws  = (float*)d_ws;

  // workspace layout (floats): Q | K | V | M | s8  = ~112 MB
  float*  Q  = ws;
  float*  Kb = ws + 8388608;   // 4096*2048
  float*  Vb = ws + 16777216;
  float*  M  = ws + 25165824;  // 2048*2048
  double* s8 = (double*)(ws + 29360128);

  dim3 blk(256);
  dim3 gbuild(16384);          // 2048*2048/256
  dim3 ggemm(16, 32);          // (2048/128, 4096/128)

  // Q = X @ Mq
  scale_kernel<<<8, blk, 0, stream>>>(wq, s8);
  build_oct_kernel<<<gbuild, blk, 0, stream>>>(wq, s8, M);
  gemm_f32<<<ggemm, blk, 0, stream>>>(x, M, Q);
  // K = X @ Mk
  scale_kernel<<<8, blk, 0, stream>>>(wk, s8);
  build_oct_kernel<<<gbuild, blk, 0, stream>>>(wk, s8, M);
  gemm_f32<<<ggemm, blk, 0, stream>>>(x, M, Kb);
  // V = X @ Mv
  scale_kernel<<<8, blk, 0, stream>>>(wv, s8);
  build_oct_kernel<<<gbuild, blk, 0, stream>>>(wv, s8, M);
  gemm_f32<<<ggemm, blk, 0, stream>>>(x, M, Vb);
  // RoPE on Q, K
  rope_kernel<<<16384, blk, 0, stream>>>(Q, Kb, fc, fs);
  // attention: O written in place into Q
  attn_kernel<<<dim3(32, 64), blk, 0, stream>>>(Q, Kb, Vb, Q);
  // mixer: Ymix(K buffer) = O @ Mmix
  build_mix_kernel<<<gbuild, blk, 0, stream>>>(wm, beta, M);
  gemm_f32<<<ggemm, blk, 0, stream>>>(Q, M, Kb);
  // out = Ymix @ Mo
  scale_kernel<<<8, blk, 0, stream>>>(wo, s8);
  build_oct_kernel<<<gbuild, blk, 0, stream>>>(wo, s8, M);
  gemm_f32<<<ggemm, blk, 0, stream>>>(Kb, M, out);
}

// Round 2
// 713.834 us; speedup vs baseline: 5.6018x; 5.6018x over previous
//
#include <hip/hip_runtime.h>
#include <math.h>

// B=4, T=1024, C=2048, H=16, D=128, c8=256, N=B*T=4096
#define CDIM 2048

typedef __bf16 bf16x8 __attribute__((ext_vector_type(8)));
typedef __bf16 bf16x4 __attribute__((ext_vector_type(4)));
typedef float  f32x4  __attribute__((ext_vector_type(4)));

__device__ __constant__ float SIGNS_c[64] = {
  1,  1,  1,  1,  1,  1,  1,  1,
  1, -1,  1, -1,  1, -1, -1,  1,
  1, -1, -1,  1,  1,  1, -1, -1,
  1,  1, -1, -1,  1, -1,  1, -1,
  1, -1, -1, -1, -1,  1,  1,  1,
  1,  1, -1,  1, -1, -1, -1,  1,
  1,  1,  1, -1, -1,  1, -1, -1,
  1, -1,  1,  1, -1, -1,  1, -1
};

__device__ __forceinline__ void load_lds16(const void* g, void* lp) {
  __builtin_amdgcn_global_load_lds(
      (const __attribute__((address_space(1))) unsigned int*)g,
      (__attribute__((address_space(3))) unsigned int*)lp, 16, 0, 0);
}

// ---- per-matrix mean(|W|) in f64 (quantization boundary is precision-sensitive) ----
__global__ void scale_kernel(const float* __restrict__ W, double* __restrict__ s8) {
  int m = blockIdx.x;
  const float* w = W + (m << 16);
  double acc = 0.0;
  for (int i = threadIdx.x; i < 65536; i += 256) acc += (double)fabsf(w[i]);
  __shared__ double red[256];
  red[threadIdx.x] = acc;
  __syncthreads();
  for (int s = 128; s > 0; s >>= 1) {
    if (threadIdx.x < s) red[threadIdx.x] += red[threadIdx.x + s];
    __syncthreads();
  }
  if (threadIdx.x == 0) s8[m] = red[0] / 65536.0 + 1e-8;
}

// ---- dense TRANSPOSED ternary matrix in bf16: MT[col][row], col=i*256+d, row=j*256+c ----
__global__ void build_oct_T(const float* __restrict__ W, const double* __restrict__ s8,
                            __bf16* __restrict__ MT) {
  int idx = blockIdx.x * 256 + threadIdx.x;   // 4M, thread-consecutive = row-consecutive
  int row = idx & 2047, col = idx >> 11;
  int i = col >> 8, d = col & 255, j = row >> 8, c = row & 255;
  int m = i ^ j;
  double s = s8[m];
  double q = rint((double)W[(m << 16) + (c << 8) + d] / s);
  q = fmin(fmax(q, -1.0), 1.0);
  MT[idx] = (__bf16)(SIGNS_c[i * 8 + j] * (float)(q * s));
}

// ---- mixer (block-diagonal, beta folded into columns), transposed, bf16 ----
__global__ void build_mix_T(const float* __restrict__ Wm, const float* __restrict__ beta,
                            __bf16* __restrict__ MT) {
  int idx = blockIdx.x * 256 + threadIdx.x;
  int row = idx & 2047, col = idx >> 11;
  int g = row >> 10, gc = col >> 10;
  float v = 0.f;
  if (g == gc) {
    int j = (row >> 7) & 7, dd = row & 127;
    int i = (col >> 7) & 7, e = col & 127;
    v = SIGNS_c[i * 8 + j] * Wm[((i ^ j) << 14) + (dd << 7) + e] * beta[e];
  }
  MT[idx] = (__bf16)v;
}

// ---- cast x f32 -> bf16 ----
__global__ void cast_x(const float* __restrict__ x, __bf16* __restrict__ xb) {
  int i = blockIdx.x * 256 + threadIdx.x;     // over 2,097,152 float4s
  float4 v = *(const float4*)(x + (size_t)i * 4);
  bf16x4 o;
  o[0] = (__bf16)v.x; o[1] = (__bf16)v.y; o[2] = (__bf16)v.z; o[3] = (__bf16)v.w;
  *(bf16x4*)(xb + (size_t)i * 4) = o;
}

// ---- m97-structure bf16 MFMA GEMM: C[4096x2048] = A[4096x2048] @ BT^T ----
// BT is B transposed: BT[col][k], row-major, 2048x2048. 128x128 tile, BK=32, 4 waves.
template<int OUT_BF16>
__global__ __launch_bounds__(256)
void gemm_bf16(const __bf16* __restrict__ A, const __bf16* __restrict__ BT,
               void* __restrict__ Cout) {
  __shared__ __align__(16) char smem[16384];  // As[128][32]b | Bs[128][32]b, 64B rows
  char* As = smem;
  char* Bs = smem + 8192;
  int tid = threadIdx.x, w = tid >> 6, l = tid & 63, hi = l >> 4, lo = l & 15;
  int wr = w >> 1, wc = w & 1;
  int bm = blockIdx.y * 128, bn = blockIdx.x * 128;
  const char* Ab = (const char*)A + (size_t)bm * 4096;
  const char* Bb = (const char*)BT + (size_t)bn * 4096;
  f32x4 acc[4][4];
  #pragma unroll
  for (int m = 0; m < 4; ++m)
    #pragma unroll
    for (int n = 0; n < 4; ++n) acc[m][n] = (f32x4){0.f, 0.f, 0.f, 0.f};

  for (int k0 = 0; k0 < CDIM; k0 += 32) {
    __syncthreads();
    #pragma unroll
    for (int q = 0; q < 2; ++q) {
      int i = q * 256 + w * 64 + l;
      int r = i >> 2, u = i & 3;                    // 4x16B chunks per 64B row
      load_lds16(Ab + (size_t)r * 4096 + k0 * 2 + u * 16, As + q * 4096 + w * 1024);
      load_lds16(Bb + (size_t)r * 4096 + k0 * 2 + u * 16, Bs + q * 4096 + w * 1024);
    }
    __syncthreads();
    bf16x8 af[4], bfr[4];
    #pragma unroll
    for (int m = 0; m < 4; ++m)
      af[m] = *(const bf16x8*)(As + (wr * 64 + m * 16 + lo) * 64 + hi * 16);
    #pragma unroll
    for (int n = 0; n < 4; ++n)
      bfr[n] = *(const bf16x8*)(Bs + (wc * 64 + n * 16 + lo) * 64 + hi * 16);
    #pragma unroll
    for (int m = 0; m < 4; ++m)
      #pragma unroll
      for (int n = 0; n < 4; ++n)
        acc[m][n] = __builtin_amdgcn_mfma_f32_16x16x32_bf16(af[m], bfr[n], acc[m][n], 0, 0, 0);
  }
  #pragma unroll
  for (int m = 0; m < 4; ++m)
    #pragma unroll
    for (int n = 0; n < 4; ++n)
      #pragma unroll
      for (int r = 0; r < 4; ++r) {
        int row = bm + wr * 64 + m * 16 + hi * 4 + r;
        int col = bn + wc * 64 + n * 16 + lo;
        float v = acc[m][n][r];
        if (OUT_BF16) ((__bf16*)Cout)[(size_t)row * CDIM + col] = (__bf16)v;
        else          ((float*)Cout)[(size_t)row * CDIM + col] = v;
      }
}

// ---- RoPE on bf16 Q,K in place ----
__global__ void rope_bf16(__bf16* __restrict__ Q, __bf16* __restrict__ K,
                          const float* __restrict__ fc, const float* __restrict__ fs) {
  int idx = blockIdx.x * 256 + threadIdx.x;   // over 1,048,576 (4 pairs each)
  int pg = idx & 15;
  int h = (idx >> 4) & 15;
  int n = idx >> 8;
  int t = n & 1023;
  float4 c4 = *(const float4*)(fc + t * 64 + pg * 4);
  float4 s4 = *(const float4*)(fs + t * 64 + pg * 4);
  float c[4] = {c4.x, c4.y, c4.z, c4.w};
  float s[4] = {s4.x, s4.y, s4.z, s4.w};
  size_t ofs = (size_t)n * CDIM + h * 128 + pg * 8;
  bf16x8 q = *(bf16x8*)(Q + ofs);
  bf16x8 k = *(bf16x8*)(K + ofs);
  bf16x8 oq, ok;
  #pragma unroll
  for (int j = 0; j < 4; ++j) {
    float x = (float)q[2 * j], y = (float)q[2 * j + 1];
    oq[2 * j]     = (__bf16)(x * c[j] - y * s[j]);
    oq[2 * j + 1] = (__bf16)(x * s[j] + y * c[j]);
    float u = (float)k[2 * j], vv = (float)k[2 * j + 1];
    ok[2 * j]     = (__bf16)(u * c[j] - vv * s[j]);
    ok[2 * j + 1] = (__bf16)(u * s[j] + vv * c[j]);
  }
  *(bf16x8*)(Q + ofs) = oq;
  *(bf16x8*)(K + ofs) = ok;
}

// ---- transpose V[b,t,h,d] -> VT[(b*16+h)*128+d][t] ----
__global__ __launch_bounds__(256)
void transpose_v(const __bf16* __restrict__ V, __bf16* __restrict__ VT) {
  __shared__ __bf16 tile[64][136];
  int tid = threadIdx.x;
  int tt = blockIdx.x;        // 16 t-tiles of 64
  int bh = blockIdx.y;        // 64
  int b = bh >> 4, h = bh & 15;
  int t0 = tt * 64;
  #pragma unroll
  for (int q = 0; q < 4; ++q) {
    int i = q * 256 + tid;
    int tr = i >> 4, u = i & 15;
    bf16x8 v = *(const bf16x8*)(V + (size_t)(b * 1024 + t0 + tr) * CDIM + h * 128 + u * 8);
    *(bf16x8*)&tile[tr][u * 8] = v;
  }
  __syncthreads();
  #pragma unroll
  for (int q = 0; q < 4; ++q) {
    int i = q * 256 + tid;
    int d = i >> 3, tu = i & 7;
    bf16x8 o;
    #pragma unroll
    for (int jj = 0; jj < 8; ++jj) o[jj] = tile[tu * 8 + jj][d];
    *(bf16x8*)(VT + ((size_t)bh * 128 + d) * 1024 + t0 + tu * 8) = o;
  }
}

// ---- MFMA flash attention, causal ----
// grid (16 qtiles of 64 rows, 64 bh), 256 thr = 4 waves, 16 q-rows/wave, KV tile 32.
__global__ __launch_bounds__(256)
void attn_mfma(const __bf16* __restrict__ Q, const __bf16* __restrict__ K,
               const __bf16* __restrict__ VT, __bf16* __restrict__ O) {
  __shared__ __align__(16) char smem[20480];
  char* Ks  = smem;            // [32][128] bf16, 256B rows, XOR-swizzled units
  char* VTs = smem + 8192;     // [128][32] bf16, 64B rows, linear
  char* Pl  = smem + 16384;    // 4 waves x [16][32] bf16
  int tid = threadIdx.x;
  int w = tid >> 6, l = tid & 63, hi = l >> 4, lo = l & 15;
  int qt = blockIdx.x, bh = blockIdx.y, b = bh >> 4, h = bh & 15;
  int qb = qt * 64;
  int qrow = qb + w * 16 + lo;
  const __bf16* qp = Q + (size_t)(b * 1024 + qrow) * CDIM + h * 128;
  bf16x8 qf[4];
  #pragma unroll
  for (int c = 0; c < 4; ++c) qf[c] = *(const bf16x8*)(qp + c * 32 + hi * 8);
  f32x4 o[8];
  #pragma unroll
  for (int n = 0; n < 8; ++n) o[n] = (f32x4){0.f, 0.f, 0.f, 0.f};
  float mrun[4], lrun[4];
  #pragma unroll
  for (int r = 0; r < 4; ++r) { mrun[r] = -1e30f; lrun[r] = 0.f; }
  int qrow_s = qb + w * 16 + hi * 4;
  int nt = qt * 2 + 2;
  const float scale = 0.08838834764831845f;
  char* Plw = Pl + w * 1024;

  for (int kt = 0; kt < nt; ++kt) {
    int k0 = kt * 32;
    __syncthreads();
    #pragma unroll
    for (int q = 0; q < 2; ++q) {
      int i = q * 256 + w * 64 + l;
      { // K tile: pre-swizzled global source, linear LDS dest (rule 21)
        int kr = i >> 4, u = i & 15, lu = u ^ (kr & 7);
        const char* g = (const char*)K + (size_t)(b * 1024 + k0 + kr) * 4096 + h * 256 + lu * 16;
        load_lds16(g, Ks + q * 4096 + w * 1024);
      }
      { // VT tile: linear, 64B rows (bank-balanced on read)
        int d = i >> 2, u = i & 3;
        const char* g = (const char*)VT + ((size_t)bh * 128 + (i >> 2)) * 2048 + k0 * 2 + u * 16;
        load_lds16(g, VTs + q * 4096 + w * 1024);
      }
    }
    __syncthreads();
    // S = Q K^T  (2 kcol frags x 4 d-chunks)
    f32x4 s[2];
    s[0] = (f32x4){0.f, 0.f, 0.f, 0.f};
    s[1] = (f32x4){0.f, 0.f, 0.f, 0.f};
    #pragma unroll
    for (int f = 0; f < 2; ++f) {
      int kr = f * 16 + lo;
      #pragma unroll
      for (int c = 0; c < 4; ++c) {
        bf16x8 kf = *(const bf16x8*)(Ks + kr * 256 + (((c * 4 + hi) ^ (kr & 7)) * 16));
        s[f] = __builtin_amdgcn_mfma_f32_16x16x32_bf16(qf[c], kf, s[f], 0, 0, 0);
      }
    }
    // mask + scale
    float sv[2][4];
    #pragma unroll
    for (int f = 0; f < 2; ++f)
      #pragma unroll
      for (int r = 0; r < 4; ++r) {
        float v = s[f][r] * scale;
        sv[f][r] = (k0 + f * 16 + lo > qrow_s + r) ? -1e30f : v;
      }
    // row max over 32 cols (16 lanes x 2 frags)
    float mx[4];
    #pragma unroll
    for (int r = 0; r < 4; ++r) mx[r] = fmaxf(sv[0][r], sv[1][r]);
    #pragma unroll
    for (int off = 1; off <= 8; off <<= 1)
      #pragma unroll
      for (int r = 0; r < 4; ++r) mx[r] = fmaxf(mx[r], __shfl_xor(mx[r], off, 64));
    float fac[4], p[2][4], rs[4];
    #pragma unroll
    for (int r = 0; r < 4; ++r) {
      float mn = fmaxf(mrun[r], mx[r]);
      fac[r] = __expf(mrun[r] - mn);
      mrun[r] = mn;
    }
    #pragma unroll
    for (int f = 0; f < 2; ++f)
      #pragma unroll
      for (int r = 0; r < 4; ++r) p[f][r] = __expf(sv[f][r] - mrun[r]);
    #pragma unroll
    for (int r = 0; r < 4; ++r) rs[r] = p[0][r] + p[1][r];
    #pragma unroll
    for (int off = 1; off <= 8; off <<= 1)
      #pragma unroll
      for (int r = 0; r < 4; ++r) rs[r] += __shfl_xor(rs[r], off, 64);
    #pragma unroll
    for (int r = 0; r < 4; ++r) lrun[r] = lrun[r] * fac[r] + rs[r];
    #pragma unroll
    for (int n = 0; n < 8; ++n)
      #pragma unroll
      for (int r = 0; r < 4; ++r) o[n][r] *= fac[r];
    // P (C-layout) -> per-wave LDS, read back in A-frag layout
    #pragma unroll
    for (int f = 0; f < 2; ++f)
      #pragma unroll
      for (int r = 0; r < 4; ++r)
        *(__bf16*)(Plw + (hi * 4 + r) * 64 + (f * 16 + lo) * 2) = (__bf16)p[f][r];
    asm volatile("s_waitcnt lgkmcnt(0)" ::: "memory");
    bf16x8 pa = *(const bf16x8*)(Plw + lo * 64 + hi * 16);
    #pragma unroll
    for (int n = 0; n < 8; ++n) {
      bf16x8 vf = *(const bf16x8*)(VTs + (n * 16 + lo) * 64 + hi * 16);
      o[n] = __builtin_amdgcn_mfma_f32_16x16x32_bf16(pa, vf, o[n], 0, 0, 0);
    }
  }
  float inv[4];
  #pragma unroll
  for (int r = 0; r < 4; ++r) inv[r] = 1.f / lrun[r];
  __bf16* op = O + (size_t)(b * 1024 + qb + w * 16) * CDIM + h * 128;
  #pragma unroll
  for (int n = 0; n < 8; ++n)
    #pragma unroll
    for (int r = 0; r < 4; ++r)
      op[(size_t)(hi * 4 + r) * CDIM + n * 16 + lo] = (__bf16)(o[n][r] * inv[r]);
}

extern "C" void kernel_launch(void* const* d_in, const int* in_sizes, int n_in,
                              void* d_out, int out_size, void* d_ws, size_t ws_size,
                              hipStream_t stream) {
  const float* x    = (const float*)d_in[0];
  const float* fc   = (const float*)d_in[1];
  const float* fs   = (const float*)d_in[2];
  const float* wq   = (const float*)d_in[3];
  const float* wk   = (const float*)d_in[4];
  const float* wv   = (const float*)d_in[5];
  const float* wo   = (const float*)d_in[6];
  const float* wm   = (const float*)d_in[7];
  const float* beta = (const float*)d_in[8];

  char* wsb = (char*)d_ws;
  __bf16* xb  = (__bf16*)(wsb);
  __bf16* Qb  = (__bf16*)(wsb + 16777216L);
  __bf16* Kb  = (__bf16*)(wsb + 2 * 16777216L);
  __bf16* Vb  = (__bf16*)(wsb + 3 * 16777216L);
  __bf16* VTb = (__bf16*)(wsb + 4 * 16777216L);
  __bf16* MT  = (__bf16*)(wsb + 5 * 16777216L);
  double* s8  = (double*)(wsb + 5 * 16777216L + 8388608L);

  dim3 blk(256);
  dim3 gbuild(16384);
  dim3 ggemm(16, 32);

  cast_x<<<8192, blk, 0, stream>>>(x, xb);

  scale_kernel<<<8, blk, 0, stream>>>(wq, s8);
  build_oct_T<<<gbuild, blk, 0, stream>>>(wq, s8, MT);
  gemm_bf16<1><<<ggemm, blk, 0, stream>>>(xb, MT, Qb);

  scale_kernel<<<8, blk, 0, stream>>>(wk, s8);
  build_oct_T<<<gbuild, blk, 0, stream>>>(wk, s8, MT);
  gemm_bf16<1><<<ggemm, blk, 0, stream>>>(xb, MT, Kb);

  scale_kernel<<<8, blk, 0, stream>>>(wv, s8);
  build_oct_T<<<gbuild, blk, 0, stream>>>(wv, s8, MT);
  gemm_bf16<1><<<ggemm, blk, 0, stream>>>(xb, MT, Vb);

  rope_bf16<<<4096, blk, 0, stream>>>(Qb, Kb, fc, fs);
  transpose_v<<<dim3(16, 64), blk, 0, stream>>>(Vb, VTb);

  attn_mfma<<<dim3(16, 64), blk, 0, stream>>>(Qb, Kb, VTb, Qb);  // O in-place

  build_mix_T<<<gbuild, blk, 0, stream>>>(wm, beta, MT);
  gemm_bf16<1><<<ggemm, blk, 0, stream>>>(Qb, MT, Vb);           // Ymix into Vb

  scale_kernel<<<8, blk, 0, stream>>>(wo, s8);
  build_oct_T<<<gbuild, blk, 0, stream>>>(wo, s8, MT);
  gemm_bf16<0><<<ggemm, blk, 0, stream>>>(Vb, MT, (float*)d_out);
}

// Round 3
// 667.033 us; speedup vs baseline: 5.9949x; 1.0702x over previous
//
#include <hip/hip_runtime.h>
#include <math.h>

#define CDIM 2048
#define QKVW 6144

typedef __bf16 bf16x8 __attribute__((ext_vector_type(8)));
typedef __bf16 bf16x4 __attribute__((ext_vector_type(4)));
typedef float  f32x4  __attribute__((ext_vector_type(4)));
typedef float  f32x16 __attribute__((ext_vector_type(16)));

__device__ __constant__ float SIGNS_c[64] = {
  1,  1,  1,  1,  1,  1,  1,  1,
  1, -1,  1, -1,  1, -1, -1,  1,
  1, -1, -1,  1,  1,  1, -1, -1,
  1,  1, -1, -1,  1, -1,  1, -1,
  1, -1, -1, -1, -1,  1,  1,  1,
  1,  1, -1,  1, -1, -1, -1,  1,
  1,  1,  1, -1, -1,  1, -1, -1,
  1, -1,  1,  1, -1, -1,  1, -1
};

__device__ __forceinline__ void load_lds16(const void* g, void* lp) {
  __builtin_amdgcn_global_load_lds(
      (const __attribute__((address_space(1))) unsigned int*)g,
      (__attribute__((address_space(3))) unsigned int*)lp, 16, 0, 0);
}

__device__ __forceinline__ unsigned pack2(float a, float b) {
  union { __bf16 h[2]; unsigned u; } x;
  x.h[0] = (__bf16)a; x.h[1] = (__bf16)b; return x.u;
}

// ---- per-matrix mean(|W|) in f64 ----
__global__ void scale_kernel(const float* __restrict__ W, double* __restrict__ s8) {
  int m = blockIdx.x;
  const float* w = W + (m << 16);
  double acc = 0.0;
  for (int i = threadIdx.x; i < 65536; i += 256) acc += (double)fabsf(w[i]);
  __shared__ double red[256];
  red[threadIdx.x] = acc;
  __syncthreads();
  for (int s = 128; s > 0; s >>= 1) {
    if (threadIdx.x < s) red[threadIdx.x] += red[threadIdx.x + s];
    __syncthreads();
  }
  if (threadIdx.x == 0) s8[m] = red[0] / 65536.0 + 1e-8;
}

// ---- transposed ternary dense matrix bf16: MT[col][row] ----
__global__ void build_oct_T(const float* __restrict__ W, const double* __restrict__ s8,
                            __bf16* __restrict__ MT) {
  int idx = blockIdx.x * 256 + threadIdx.x;
  int row = idx & 2047, col = idx >> 11;
  int i = col >> 8, d = col & 255, j = row >> 8, c = row & 255;
  int m = i ^ j;
  double s = s8[m];
  double q = rint((double)W[(m << 16) + (c << 8) + d] / s);
  q = fmin(fmax(q, -1.0), 1.0);
  MT[idx] = (__bf16)(SIGNS_c[i * 8 + j] * (float)(q * s));
}

// ---- mixer block (1024x1024, shared by both groups), transposed, beta folded ----
__global__ void build_mix_T(const float* __restrict__ Wm, const float* __restrict__ beta,
                            __bf16* __restrict__ MT) {
  int idx = blockIdx.x * 256 + threadIdx.x;   // 1M
  int row = idx & 1023, col = idx >> 10;
  int j = row >> 7, dd = row & 127;
  int i = col >> 7, e = col & 127;
  MT[idx] = (__bf16)(SIGNS_c[i * 8 + j] * Wm[((i ^ j) << 14) + (dd << 7) + e] * beta[e]);
}

__global__ void cast_x(const float* __restrict__ x, __bf16* __restrict__ xb) {
  int i = blockIdx.x * 256 + threadIdx.x;
  float4 v = *(const float4*)(x + (size_t)i * 4);
  bf16x4 o;
  o[0] = (__bf16)v.x; o[1] = (__bf16)v.y; o[2] = (__bf16)v.z; o[3] = (__bf16)v.w;
  *(bf16x4*)(xb + (size_t)i * 4) = o;
}

// ---- parameterized bf16 MFMA GEMM (m97 structure): C[M x N] = A[M x K] @ BT^T ----
template<int OUT_BF16>
__global__ __launch_bounds__(256)
void gemm_bf16(const __bf16* __restrict__ A, int lda,
               const __bf16* __restrict__ BT, int ldb,
               void* __restrict__ Cout, int ldc, int K, int az, int cz) {
  __shared__ __align__(16) char smem[16384];
  char* As = smem;
  char* Bs = smem + 8192;
  int tid = threadIdx.x, w = tid >> 6, l = tid & 63, hi = l >> 4, lo = l & 15;
  int wr = w >> 1, wc = w & 1;
  int bm = blockIdx.y * 128, bn = blockIdx.x * 128;
  const __bf16* Az = A + (size_t)blockIdx.z * az;
  const char* Ab = (const char*)Az + (size_t)bm * lda * 2;
  const char* Bb = (const char*)BT + (size_t)bn * ldb * 2;
  size_t ldab = (size_t)lda * 2, ldbb = (size_t)ldb * 2;
  f32x4 acc[4][4];
  #pragma unroll
  for (int m = 0; m < 4; ++m)
    #pragma unroll
    for (int n = 0; n < 4; ++n) acc[m][n] = (f32x4){0.f, 0.f, 0.f, 0.f};

  for (int k0 = 0; k0 < K; k0 += 32) {
    __syncthreads();
    #pragma unroll
    for (int q = 0; q < 2; ++q) {
      int i = q * 256 + w * 64 + l;
      int r = i >> 2, u = i & 3;
      load_lds16(Ab + (size_t)r * ldab + k0 * 2 + u * 16, As + q * 4096 + w * 1024);
      load_lds16(Bb + (size_t)r * ldbb + k0 * 2 + u * 16, Bs + q * 4096 + w * 1024);
    }
    __syncthreads();
    bf16x8 af[4], bfr[4];
    #pragma unroll
    for (int m = 0; m < 4; ++m)
      af[m] = *(const bf16x8*)(As + (wr * 64 + m * 16 + lo) * 64 + hi * 16);
    #pragma unroll
    for (int n = 0; n < 4; ++n)
      bfr[n] = *(const bf16x8*)(Bs + (wc * 64 + n * 16 + lo) * 64 + hi * 16);
    #pragma unroll
    for (int m = 0; m < 4; ++m)
      #pragma unroll
      for (int n = 0; n < 4; ++n)
        acc[m][n] = __builtin_amdgcn_mfma_f32_16x16x32_bf16(af[m], bfr[n], acc[m][n], 0, 0, 0);
  }
  #pragma unroll
  for (int m = 0; m < 4; ++m)
    #pragma unroll
    for (int n = 0; n < 4; ++n)
      #pragma unroll
      for (int r = 0; r < 4; ++r) {
        int row = bm + wr * 64 + m * 16 + hi * 4 + r;
        int col = bn + wc * 64 + n * 16 + lo;
        float v = acc[m][n][r];
        if (OUT_BF16)
          ((__bf16*)Cout)[(size_t)blockIdx.z * cz + (size_t)row * ldc + col] = (__bf16)v;
        else
          ((float*)Cout)[(size_t)blockIdx.z * cz + (size_t)row * ldc + col] = v;
      }
}

// ---- RoPE on Q,K columns of QKV (stride 6144) ----
__global__ void rope_bf16(__bf16* __restrict__ QKV,
                          const float* __restrict__ fc, const float* __restrict__ fs) {
  int idx = blockIdx.x * 256 + threadIdx.x;   // 4096*16*16
  int pg = idx & 15;
  int h = (idx >> 4) & 15;
  int n = idx >> 8;
  int t = n & 1023;
  float4 c4 = *(const float4*)(fc + t * 64 + pg * 4);
  float4 s4 = *(const float4*)(fs + t * 64 + pg * 4);
  float c[4] = {c4.x, c4.y, c4.z, c4.w};
  float s[4] = {s4.x, s4.y, s4.z, s4.w};
  size_t ofs = (size_t)n * QKVW + h * 128 + pg * 8;
  bf16x8 q = *(bf16x8*)(QKV + ofs);
  bf16x8 k = *(bf16x8*)(QKV + 2048 + ofs);
  bf16x8 oq, ok;
  #pragma unroll
  for (int j = 0; j < 4; ++j) {
    float x = (float)q[2 * j], y = (float)q[2 * j + 1];
    oq[2 * j]     = (__bf16)(x * c[j] - y * s[j]);
    oq[2 * j + 1] = (__bf16)(x * s[j] + y * c[j]);
    float u = (float)k[2 * j], vv = (float)k[2 * j + 1];
    ok[2 * j]     = (__bf16)(u * c[j] - vv * s[j]);
    ok[2 * j + 1] = (__bf16)(u * s[j] + vv * c[j]);
  }
  *(bf16x8*)(QKV + ofs) = oq;
  *(bf16x8*)(QKV + 2048 + ofs) = ok;
}

// ---- transpose V cols of QKV -> VT[(bh*128+d)][t] ----
__global__ __launch_bounds__(256)
void transpose_v(const __bf16* __restrict__ QKV, __bf16* __restrict__ VT) {
  __shared__ __bf16 tile[64][136];
  int tid = threadIdx.x;
  int tt = blockIdx.x;
  int bh = blockIdx.y;
  int b = bh >> 4, h = bh & 15;
  int t0 = tt * 64;
  #pragma unroll
  for (int q = 0; q < 4; ++q) {
    int i = q * 256 + tid;
    int tr = i >> 4, u = i & 15;
    bf16x8 v = *(const bf16x8*)(QKV + (size_t)(b * 1024 + t0 + tr) * QKVW + 4096 + h * 128 + u * 8);
    *(bf16x8*)&tile[tr][u * 8] = v;
  }
  __syncthreads();
  #pragma unroll
  for (int q = 0; q < 4; ++q) {
    int i = q * 256 + tid;
    int d = i >> 3, tu = i & 7;
    bf16x8 o;
    #pragma unroll
    for (int jj = 0; jj < 8; ++jj) o[jj] = tile[tu * 8 + jj][d];
    *(bf16x8*)(VT + ((size_t)bh * 128 + d) * 1024 + t0 + tu * 8) = o;
  }
}

// ---- 32x32 MFMA flash attention, causal, swapped operands ----
// grid (16, 64) reversed-x, block 128 = 2 waves, 32 q-rows/wave, KVBLK=64.
// O written in-place into Q columns of QKV (disjoint from K/V columns).
__global__ __launch_bounds__(128)
void attn_mfma2(__bf16* __restrict__ QKV, const __bf16* __restrict__ VT) {
  __shared__ __align__(16) char smem[32768];
  char* Ks  = smem;          // [64][128] bf16, 256B rows, 16B granule g -> src g^(row&7)
  char* VTs = smem + 16384;  // [128][64] bf16, 128B rows, granule g -> src g^(row&7)
  int tid = threadIdx.x;
  int w = tid >> 6, l = tid & 63;
  int lo = l & 31, hv = l >> 5;
  int qt = (int)gridDim.x - 1 - (int)blockIdx.x;
  int bh = blockIdx.y, b = bh >> 4, h = bh & 15;
  int qb = qt * 64;
  int qrow = qb + w * 32 + lo;
  const __bf16* qp = QKV + (size_t)(b * 1024 + qrow) * QKVW + h * 128;
  bf16x8 qf[8];
  #pragma unroll
  for (int c = 0; c < 8; ++c) qf[c] = *(const bf16x8*)(qp + c * 16 + hv * 8);

  f32x16 o[4];
  #pragma unroll
  for (int n = 0; n < 4; ++n)
    #pragma unroll
    for (int r = 0; r < 16; ++r) o[n][r] = 0.f;
  float mrun = -1e30f, lrun = 0.f;
  const float scale = 0.08838834764831845f;
  int src0 = lo, src1 = 32 + lo;

  for (int kt = 0; kt <= qt; ++kt) {
    int k0 = kt * 64;
    __syncthreads();
    if (w == 0) {
      #pragma unroll
      for (int i = 0; i < 16; ++i) {
        int e = i * 64 + l;
        int row = e >> 4, g = e & 15;
        int gs = g ^ (row & 7);
        const char* src = (const char*)QKV +
            ((size_t)(b * 1024 + k0 + row) * QKVW + 2048 + h * 128) * 2 + gs * 16;
        load_lds16(src, Ks + i * 1024);
      }
    } else {
      #pragma unroll
      for (int i = 0; i < 16; ++i) {
        int e = i * 64 + l;
        int row = e >> 3, g = e & 7;
        int gs = g ^ (row & 7);
        const char* src = (const char*)VT +
            ((size_t)(bh * 128 + row) * 1024 + k0) * 2 + gs * 16;
        load_lds16(src, VTs + i * 1024);
      }
    }
    __syncthreads();

    // S^T = K x Q^T : lane holds S[q=lo][k = kk*32 + (reg&3)+8*(reg>>2)+4*hv]
    f32x16 sT[2];
    #pragma unroll
    for (int kk = 0; kk < 2; ++kk) {
      #pragma unroll
      for (int r = 0; r < 16; ++r) sT[kk][r] = 0.f;
      #pragma unroll
      for (int c = 0; c < 8; ++c) {
        bf16x8 kf = *(const bf16x8*)(Ks + (kk * 32 + lo) * 256 + (((2 * c + hv) ^ (lo & 7)) * 16));
        sT[kk] = __builtin_amdgcn_mfma_f32_32x32x16_bf16(kf, qf[c], sT[kk], 0, 0, 0);
      }
    }
    bool diag = (kt == qt);
    float pv[2][16];
    #pragma unroll
    for (int kk = 0; kk < 2; ++kk)
      #pragma unroll
      for (int r = 0; r < 16; ++r) {
        float v = sT[kk][r] * scale;
        if (diag) {
          int kg = k0 + kk * 32 + (r & 3) + 8 * (r >> 2) + 4 * hv;
          if (kg > qrow) v = -1e30f;
        }
        pv[kk][r] = v;
      }
    float mx = pv[0][0];
    #pragma unroll
    for (int kk = 0; kk < 2; ++kk)
      #pragma unroll
      for (int r = 0; r < 16; ++r) mx = fmaxf(mx, pv[kk][r]);
    mx = fmaxf(mx, __shfl_xor(mx, 32, 64));
    float mnew = fmaxf(mrun, mx);
    float fac = __expf(mrun - mnew);
    float rs = 0.f;
    #pragma unroll
    for (int kk = 0; kk < 2; ++kk)
      #pragma unroll
      for (int r = 0; r < 16; ++r) {
        float p = __expf(pv[kk][r] - mnew);
        pv[kk][r] = p;
        rs += p;
      }
    rs += __shfl_xor(rs, 32, 64);
    lrun = lrun * fac + rs;
    mrun = mnew;
    #pragma unroll
    for (int n = 0; n < 4; ++n)
      #pragma unroll
      for (int r = 0; r < 16; ++r) o[n][r] *= fac;

    // pack p -> bf16 pairs: pk[kk][m][u] = (k=8m+4hv+2u, +1)
    unsigned pk[2][4][2];
    #pragma unroll
    for (int kk = 0; kk < 2; ++kk)
      #pragma unroll
      for (int m = 0; m < 4; ++m)
        #pragma unroll
        for (int u = 0; u < 2; ++u)
          pk[kk][m][u] = pack2(pv[kk][m * 4 + 2 * u], pv[kk][m * 4 + 2 * u + 1]);

    // PV: O^T += VT x P ; B-frag word t = pk[kk][2s+hv][t&1] from lane src_{t>>1}
    #pragma unroll
    for (int kk = 0; kk < 2; ++kk) {
      #pragma unroll
      for (int s = 0; s < 2; ++s) {
        unsigned a0 = __shfl(pk[kk][2 * s][0], src0, 64);
        unsigned b0 = __shfl(pk[kk][2 * s + 1][0], src0, 64);
        unsigned a1 = __shfl(pk[kk][2 * s][1], src0, 64);
        unsigned b1 = __shfl(pk[kk][2 * s + 1][1], src0, 64);
        unsigned a2 = __shfl(pk[kk][2 * s][0], src1, 64);
        unsigned b2 = __shfl(pk[kk][2 * s + 1][0], src1, 64);
        unsigned a3 = __shfl(pk[kk][2 * s][1], src1, 64);
        unsigned b3 = __shfl(pk[kk][2 * s + 1][1], src1, 64);
        union { unsigned u[4]; bf16x8 v; } pb;
        pb.u[0] = hv ? b0 : a0;
        pb.u[1] = hv ? b1 : a1;
        pb.u[2] = hv ? b2 : a2;
        pb.u[3] = hv ? b3 : a3;
        int ks16 = 2 * kk + s;
        #pragma unroll
        for (int n = 0; n < 4; ++n) {
          bf16x8 vf = *(const bf16x8*)(VTs + (n * 32 + lo) * 128 +
                                       (((2 * ks16 + hv) ^ (lo & 7)) * 16));
          o[n] = __builtin_amdgcn_mfma_f32_32x32x16_bf16(vf, pb.v, o[n], 0, 0, 0);
        }
      }
    }
  }
  float inv = 1.f / lrun;
  __bf16* op = QKV + (size_t)(b * 1024 + qrow) * QKVW + h * 128;  // O into Q cols
  #pragma unroll
  for (int n = 0; n < 4; ++n)
    #pragma unroll
    for (int m4 = 0; m4 < 4; ++m4) {
      bf16x4 ov;
      #pragma unroll
      for (int j = 0; j < 4; ++j) ov[j] = (__bf16)(o[n][m4 * 4 + j] * inv);
      *(bf16x4*)(op + n * 32 + 8 * m4 + 4 * hv) = ov;
    }
}

extern "C" void kernel_launch(void* const* d_in, const int* in_sizes, int n_in,
                              void* d_out, int out_size, void* d_ws, size_t ws_size,
                              hipStream_t stream) {
  const float* x    = (const float*)d_in[0];
  const float* fc   = (const float*)d_in[1];
  const float* fs   = (const float*)d_in[2];
  const float* wq   = (const float*)d_in[3];
  const float* wk   = (const float*)d_in[4];
  const float* wv   = (const float*)d_in[5];
  const float* wo   = (const float*)d_in[6];
  const float* wm   = (const float*)d_in[7];
  const float* beta = (const float*)d_in[8];

  char* wsb = (char*)d_ws;
  __bf16* xb    = (__bf16*)(wsb);                    // 16MB (reused: MTmix)
  __bf16* MTqkv = (__bf16*)(wsb + 16777216L);        // 24MB (reused: MTwo)
  __bf16* QKV   = (__bf16*)(wsb + 41943040L);        // 48MB
  __bf16* VTb   = (__bf16*)(wsb + 92274688L);        // 16MB (reused: Ymix)
  double* s8    = (double*)(wsb + 109051904L);       // 24 doubles
  __bf16* MTmix = xb;
  __bf16* MTwo  = MTqkv;
  __bf16* Ymix  = VTb;

  dim3 blk(256);

  cast_x<<<8192, blk, 0, stream>>>(x, xb);
  scale_kernel<<<8, blk, 0, stream>>>(wq, s8);
  scale_kernel<<<8, blk, 0, stream>>>(wk, s8 + 8);
  scale_kernel<<<8, blk, 0, stream>>>(wv, s8 + 16);
  build_oct_T<<<16384, blk, 0, stream>>>(wq, s8,      MTqkv);
  build_oct_T<<<16384, blk, 0, stream>>>(wk, s8 + 8,  MTqkv + 4194304L);
  build_oct_T<<<16384, blk, 0, stream>>>(wv, s8 + 16, MTqkv + 8388608L);

  // QKV = xb @ [Mq|Mk|Mv]
  gemm_bf16<1><<<dim3(48, 32, 1), blk, 0, stream>>>(xb, 2048, MTqkv, 2048, QKV, QKVW, 2048, 0, 0);

  rope_bf16<<<4096, blk, 0, stream>>>(QKV, fc, fs);
  transpose_v<<<dim3(16, 64), blk, 0, stream>>>(QKV, VTb);

  attn_mfma2<<<dim3(16, 64), dim3(128), 0, stream>>>(QKV, VTb);

  // mixer: block-diagonal -> 2 batched GEMMs over groups (z)
  build_mix_T<<<4096, blk, 0, stream>>>(wm, beta, MTmix);
  gemm_bf16<1><<<dim3(8, 32, 2), blk, 0, stream>>>(QKV, QKVW, MTmix, 1024, Ymix, 2048, 1024, 1024, 1024);

  scale_kernel<<<8, blk, 0, stream>>>(wo, s8);
  build_oct_T<<<16384, blk, 0, stream>>>(wo, s8, MTwo);
  gemm_bf16<0><<<dim3(16, 32, 1), blk, 0, stream>>>(Ymix, 2048, MTwo, 2048, (float*)d_out, 2048, 2048, 0, 0);
}

// Round 4
// 459.761 us; speedup vs baseline: 8.6975x; 1.4508x over previous
//
#include <hip/hip_runtime.h>
#include <math.h>

#define CDIM 2048
#define QKVW 6144

typedef __bf16 bf16x8 __attribute__((ext_vector_type(8)));
typedef __bf16 bf16x4 __attribute__((ext_vector_type(4)));
typedef float  f32x4  __attribute__((ext_vector_type(4)));
typedef float  f32x16 __attribute__((ext_vector_type(16)));

__device__ __constant__ float SIGNS_c[64] = {
  1,  1,  1,  1,  1,  1,  1,  1,
  1, -1,  1, -1,  1, -1, -1,  1,
  1, -1, -1,  1,  1,  1, -1, -1,
  1,  1, -1, -1,  1, -1,  1, -1,
  1, -1, -1, -1, -1,  1,  1,  1,
  1,  1, -1,  1, -1, -1, -1,  1,
  1,  1,  1, -1, -1,  1, -1, -1,
  1, -1,  1,  1, -1, -1,  1, -1
};

__device__ __forceinline__ void load_lds16(const void* g, void* lp) {
  __builtin_amdgcn_global_load_lds(
      (const __attribute__((address_space(1))) unsigned int*)g,
      (__attribute__((address_space(3))) unsigned int*)lp, 16, 0, 0);
}

__device__ __forceinline__ void wg_barrier() {
  asm volatile("" ::: "memory");
  __builtin_amdgcn_s_barrier();
  asm volatile("" ::: "memory");
}

__device__ __forceinline__ unsigned pack2(float a, float b) {
  union { __bf16 h[2]; unsigned u; } x;
  x.h[0] = (__bf16)a; x.h[1] = (__bf16)b; return x.u;
}

// ---- mean(|W|) in f64 for all 4 weight tensors in one dispatch ----
__global__ void scale4_kernel(const float* __restrict__ wq, const float* __restrict__ wk,
                              const float* __restrict__ wv, const float* __restrict__ wo,
                              double* __restrict__ s8) {
  int which = blockIdx.x >> 3, m = blockIdx.x & 7;
  const float* W = (which == 0) ? wq : (which == 1) ? wk : (which == 2) ? wv : wo;
  const float* w = W + (m << 16);
  double acc = 0.0;
  for (int i = threadIdx.x; i < 65536; i += 256) acc += (double)fabsf(w[i]);
  __shared__ double red[256];
  red[threadIdx.x] = acc;
  __syncthreads();
  for (int s = 128; s > 0; s >>= 1) {
    if (threadIdx.x < s) red[threadIdx.x] += red[threadIdx.x + s];
    __syncthreads();
  }
  if (threadIdx.x == 0) s8[which * 8 + m] = red[0] / 65536.0 + 1e-8;
}

// ---- transposed ternary dense matrices for q,k,v in one dispatch ----
__global__ void build_oct3(const float* __restrict__ wq, const float* __restrict__ wk,
                           const float* __restrict__ wv, const double* __restrict__ s8,
                           __bf16* __restrict__ MT) {
  int z = blockIdx.y;
  const float* W = (z == 0) ? wq : (z == 1) ? wk : wv;
  const double* sp = s8 + z * 8;
  __bf16* out = MT + (size_t)z * 4194304;
  int idx = blockIdx.x * 256 + threadIdx.x;
  int row = idx & 2047, col = idx >> 11;
  int i = col >> 8, d = col & 255, j = row >> 8, c = row & 255;
  int m = i ^ j;
  double s = sp[m];
  double q = rint((double)W[(m << 16) + (c << 8) + d] / s);
  q = fmin(fmax(q, -1.0), 1.0);
  out[idx] = (__bf16)(SIGNS_c[i * 8 + j] * (float)(q * s));
}

__global__ void build_oct_T(const float* __restrict__ W, const double* __restrict__ s8,
                            __bf16* __restrict__ MT) {
  int idx = blockIdx.x * 256 + threadIdx.x;
  int row = idx & 2047, col = idx >> 11;
  int i = col >> 8, d = col & 255, j = row >> 8, c = row & 255;
  int m = i ^ j;
  double s = s8[m];
  double q = rint((double)W[(m << 16) + (c << 8) + d] / s);
  q = fmin(fmax(q, -1.0), 1.0);
  MT[idx] = (__bf16)(SIGNS_c[i * 8 + j] * (float)(q * s));
}

__global__ void build_mix_T(const float* __restrict__ Wm, const float* __restrict__ beta,
                            __bf16* __restrict__ MT) {
  int idx = blockIdx.x * 256 + threadIdx.x;
  int row = idx & 1023, col = idx >> 10;
  int j = row >> 7, dd = row & 127;
  int i = col >> 7, e = col & 127;
  MT[idx] = (__bf16)(SIGNS_c[i * 8 + j] * Wm[((i ^ j) << 14) + (dd << 7) + e] * beta[e]);
}

__global__ void cast_x(const float* __restrict__ x, __bf16* __restrict__ xb) {
  int i = blockIdx.x * 256 + threadIdx.x;
  float4 v = *(const float4*)(x + (size_t)i * 4);
  bf16x4 o;
  o[0] = (__bf16)v.x; o[1] = (__bf16)v.y; o[2] = (__bf16)v.z; o[3] = (__bf16)v.w;
  *(bf16x4*)(xb + (size_t)i * 4) = o;
}

// ---- phase-split counted-vmcnt GEMM: QKV[4096x6144] = xb[4096x2048] @ MT^T ----
// BM=256 BN=192 BK=32, 8 waves (2x4), dbuf 64KB, depth-2 prefetch, XOR-swizzled LDS.
__global__ __launch_bounds__(512, 2)
void gemm_qkv(const __bf16* __restrict__ A, const __bf16* __restrict__ BT,
              __bf16* __restrict__ C) {
  __shared__ __align__(16) char smem[65536];   // buf b at b*32768: As 16KB | Bs 16KB
  int tid = threadIdx.x;
  int w = tid >> 6, l = tid & 63, hi = l >> 4, lo = l & 15;
  int wm = w >> 2, wn = w & 3;
  // XCD-aware bijective swizzle (512 blocks, 512%8==0)
  int lin = blockIdx.x;
  int s = (lin & 7) * 64 + (lin >> 3);
  int by = s >> 5, bx = s & 31;                // NXB = 32
  int bm = by * 256, bn = bx * 192;
  const char* Ab = (const char*)(A + (size_t)bm * 2048);
  const char* Bb = (const char*)(BT + (size_t)bn * 2048);

  // frag read bases (swizzled): lds-row = row>>1 (128B), slot = ((row&1)*4+hi)^(row>>1 &7)
  int sw = (((lo & 1) << 2) + hi) ^ (lo >> 1);
  int base_a = (wm * 64 + (lo >> 1)) * 128 + sw * 16;
  int base_b = 16384 + (wn * 24 + (lo >> 1)) * 128 + sw * 16;

  // staging: thread covers granules e = q*512+tid of the 1024-granule tile.
  // lds (lr, sl) holds logical (row = lr*2 + (x>>2), g = x&3), x = sl ^ (lr&7).
  int se_r[2], se_g[2];
  #pragma unroll
  for (int q = 0; q < 2; ++q) {
    int e = q * 512 + tid;
    int lr = e >> 3, sl = e & 7;
    int x = sl ^ (lr & 7);
    se_r[q] = lr * 2 + (x >> 2);
    se_g[q] = x & 3;
  }
  int dstoff[2] = { (0 * 512 + w * 64) * 16, (1 * 512 + w * 64) * 16 };

  f32x4 acc[8][3];
  #pragma unroll
  for (int m = 0; m < 8; ++m)
    #pragma unroll
    for (int n = 0; n < 3; ++n) acc[m][n] = (f32x4){0.f, 0.f, 0.f, 0.f};

  #define STAGE(BUFI, K0) do {                                              \
    char* As_ = smem + (BUFI) * 32768;                                      \
    char* Bs_ = As_ + 16384;                                                \
    _Pragma("unroll")                                                       \
    for (int q = 0; q < 2; ++q) {                                           \
      size_t go = (size_t)se_r[q] * 4096 + (size_t)(K0) * 2 + se_g[q] * 16; \
      load_lds16(Ab + go, As_ + dstoff[q]);                                 \
      load_lds16(Bb + go, Bs_ + dstoff[q]);                                 \
    }                                                                       \
  } while (0)

  const int NT = 64;                           // 2048 / 32
  STAGE(0, 0);
  STAGE(1, 32);
  asm volatile("s_waitcnt vmcnt(4)" ::: "memory");
  wg_barrier();

  for (int t = 0; t < NT; ++t) {
    char* buf = smem + (t & 1) * 32768;
    bf16x8 bfr[3], afr[8];
    #pragma unroll
    for (int n = 0; n < 3; ++n) bfr[n] = *(const bf16x8*)(buf + base_b + n * 1024);
    #pragma unroll
    for (int m = 0; m < 8; ++m) afr[m] = *(const bf16x8*)(buf + base_a + m * 1024);
    __builtin_amdgcn_s_setprio(1);
    #pragma unroll
    for (int m = 0; m < 4; ++m)
      #pragma unroll
      for (int n = 0; n < 3; ++n)
        acc[m][n] = __builtin_amdgcn_mfma_f32_16x16x32_bf16(afr[m], bfr[n], acc[m][n], 0, 0, 0);
    __builtin_amdgcn_s_setprio(0);
    wg_barrier();                              // all reads of buf done

    if (t + 2 < NT) STAGE(t & 1, (t + 2) * 32);
    __builtin_amdgcn_s_setprio(1);
    #pragma unroll
    for (int m = 4; m < 8; ++m)
      #pragma unroll
      for (int n = 0; n < 3; ++n)
        acc[m][n] = __builtin_amdgcn_mfma_f32_16x16x32_bf16(afr[m], bfr[n], acc[m][n], 0, 0, 0);
    __builtin_amdgcn_s_setprio(0);
    if (t + 2 < NT) { asm volatile("s_waitcnt vmcnt(4)" ::: "memory"); }
    else            { asm volatile("s_waitcnt vmcnt(0)" ::: "memory"); }
    wg_barrier();                              // tile t+1 visible
  }
  #undef STAGE

  #pragma unroll
  for (int m = 0; m < 8; ++m)
    #pragma unroll
    for (int n = 0; n < 3; ++n)
      #pragma unroll
      for (int r = 0; r < 4; ++r) {
        int row = bm + wm * 128 + m * 16 + hi * 4 + r;
        int col = bn + wn * 48 + n * 16 + lo;
        C[(size_t)row * QKVW + col] = (__bf16)acc[m][n][r];
      }
}

// ---- m97-structure bf16 GEMM (kept for mixer / final) ----
template<int OUT_BF16>
__global__ __launch_bounds__(256)
void gemm_bf16(const __bf16* __restrict__ A, int lda,
               const __bf16* __restrict__ BT, int ldb,
               void* __restrict__ Cout, int ldc, int K, int az, int cz) {
  __shared__ __align__(16) char smem[16384];
  char* As = smem;
  char* Bs = smem + 8192;
  int tid = threadIdx.x, w = tid >> 6, l = tid & 63, hi = l >> 4, lo = l & 15;
  int wr = w >> 1, wc = w & 1;
  int bm = blockIdx.y * 128, bn = blockIdx.x * 128;
  const __bf16* Az = A + (size_t)blockIdx.z * az;
  const char* Ab = (const char*)Az + (size_t)bm * lda * 2;
  const char* Bb = (const char*)BT + (size_t)bn * ldb * 2;
  size_t ldab = (size_t)lda * 2, ldbb = (size_t)ldb * 2;
  f32x4 acc[4][4];
  #pragma unroll
  for (int m = 0; m < 4; ++m)
    #pragma unroll
    for (int n = 0; n < 4; ++n) acc[m][n] = (f32x4){0.f, 0.f, 0.f, 0.f};

  for (int k0 = 0; k0 < K; k0 += 32) {
    __syncthreads();
    #pragma unroll
    for (int q = 0; q < 2; ++q) {
      int i = q * 256 + w * 64 + l;
      int r = i >> 2, u = i & 3;
      load_lds16(Ab + (size_t)r * ldab + k0 * 2 + u * 16, As + q * 4096 + w * 1024);
      load_lds16(Bb + (size_t)r * ldbb + k0 * 2 + u * 16, Bs + q * 4096 + w * 1024);
    }
    __syncthreads();
    bf16x8 af[4], bfr[4];
    #pragma unroll
    for (int m = 0; m < 4; ++m)
      af[m] = *(const bf16x8*)(As + (wr * 64 + m * 16 + lo) * 64 + hi * 16);
    #pragma unroll
    for (int n = 0; n < 4; ++n)
      bfr[n] = *(const bf16x8*)(Bs + (wc * 64 + n * 16 + lo) * 64 + hi * 16);
    #pragma unroll
    for (int m = 0; m < 4; ++m)
      #pragma unroll
      for (int n = 0; n < 4; ++n)
        acc[m][n] = __builtin_amdgcn_mfma_f32_16x16x32_bf16(af[m], bfr[n], acc[m][n], 0, 0, 0);
  }
  #pragma unroll
  for (int m = 0; m < 4; ++m)
    #pragma unroll
    for (int n = 0; n < 4; ++n)
      #pragma unroll
      for (int r = 0; r < 4; ++r) {
        int row = bm + wr * 64 + m * 16 + hi * 4 + r;
        int col = bn + wc * 64 + n * 16 + lo;
        float v = acc[m][n][r];
        if (OUT_BF16)
          ((__bf16*)Cout)[(size_t)blockIdx.z * cz + (size_t)row * ldc + col] = (__bf16)v;
        else
          ((float*)Cout)[(size_t)blockIdx.z * cz + (size_t)row * ldc + col] = v;
      }
}

// ---- RoPE on Q,K columns of QKV ----
__global__ void rope_bf16(__bf16* __restrict__ QKV,
                          const float* __restrict__ fc, const float* __restrict__ fs) {
  int idx = blockIdx.x * 256 + threadIdx.x;
  int pg = idx & 15;
  int h = (idx >> 4) & 15;
  int n = idx >> 8;
  int t = n & 1023;
  float4 c4 = *(const float4*)(fc + t * 64 + pg * 4);
  float4 s4 = *(const float4*)(fs + t * 64 + pg * 4);
  float c[4] = {c4.x, c4.y, c4.z, c4.w};
  float s[4] = {s4.x, s4.y, s4.z, s4.w};
  size_t ofs = (size_t)n * QKVW + h * 128 + pg * 8;
  bf16x8 q = *(bf16x8*)(QKV + ofs);
  bf16x8 k = *(bf16x8*)(QKV + 2048 + ofs);
  bf16x8 oq, ok;
  #pragma unroll
  for (int j = 0; j < 4; ++j) {
    float x = (float)q[2 * j], y = (float)q[2 * j + 1];
    oq[2 * j]     = (__bf16)(x * c[j] - y * s[j]);
    oq[2 * j + 1] = (__bf16)(x * s[j] + y * c[j]);
    float u = (float)k[2 * j], vv = (float)k[2 * j + 1];
    ok[2 * j]     = (__bf16)(u * c[j] - vv * s[j]);
    ok[2 * j + 1] = (__bf16)(u * s[j] + vv * c[j]);
  }
  *(bf16x8*)(QKV + ofs) = oq;
  *(bf16x8*)(QKV + 2048 + ofs) = ok;
}

// ---- transpose V cols of QKV -> VT[(bh*128+d)][t] ----
__global__ __launch_bounds__(256)
void transpose_v(const __bf16* __restrict__ QKV, __bf16* __restrict__ VT) {
  __shared__ __bf16 tile[64][136];
  int tid = threadIdx.x;
  int tt = blockIdx.x;
  int bh = blockIdx.y;
  int b = bh >> 4, h = bh & 15;
  int t0 = tt * 64;
  #pragma unroll
  for (int q = 0; q < 4; ++q) {
    int i = q * 256 + tid;
    int tr = i >> 4, u = i & 15;
    bf16x8 v = *(const bf16x8*)(QKV + (size_t)(b * 1024 + t0 + tr) * QKVW + 4096 + h * 128 + u * 8);
    *(bf16x8*)&tile[tr][u * 8] = v;
  }
  __syncthreads();
  #pragma unroll
  for (int q = 0; q < 4; ++q) {
    int i = q * 256 + tid;
    int d = i >> 3, tu = i & 7;
    bf16x8 o;
    #pragma unroll
    for (int jj = 0; jj < 8; ++jj) o[jj] = tile[tu * 8 + jj][d];
    *(bf16x8*)(VT + ((size_t)bh * 128 + d) * 1024 + t0 + tu * 8) = o;
  }
}

// ---- 32x32 MFMA flash attention, causal, swapped operands, exp2-domain ----
__global__ __launch_bounds__(128)
void attn_mfma2(__bf16* __restrict__ QKV, const __bf16* __restrict__ VT) {
  __shared__ __align__(16) char smem[32768];
  char* Ks  = smem;          // [64][128] bf16, swizzled granules
  char* VTs = smem + 16384;  // [128][64] bf16, swizzled granules
  int tid = threadIdx.x;
  int w = tid >> 6, l = tid & 63;
  int lo = l & 31, hv = l >> 5;
  int qt = (int)gridDim.x - 1 - (int)blockIdx.x;
  int bh = blockIdx.y, b = bh >> 4, h = bh & 15;
  int qb = qt * 64;
  int qrow = qb + w * 32 + lo;
  const __bf16* qp = QKV + (size_t)(b * 1024 + qrow) * QKVW + h * 128;
  bf16x8 qf[8];
  #pragma unroll
  for (int c = 0; c < 8; ++c) qf[c] = *(const bf16x8*)(qp + c * 16 + hv * 8);

  f32x16 o[4];
  #pragma unroll
  for (int n = 0; n < 4; ++n)
    #pragma unroll
    for (int r = 0; r < 16; ++r) o[n][r] = 0.f;
  float mrun = -1e30f, lrun = 0.f;
  const float SCL = 0.08838834764831845f * 1.4426950408889634f;  // scale * log2(e)
  int src0 = lo, src1 = 32 + lo;

  for (int kt = 0; kt <= qt; ++kt) {
    int k0 = kt * 64;
    __syncthreads();
    if (w == 0) {
      #pragma unroll
      for (int i = 0; i < 16; ++i) {
        int e = i * 64 + l;
        int row = e >> 4, g = e & 15;
        int gs = g ^ (row & 7);
        const char* src = (const char*)QKV +
            ((size_t)(b * 1024 + k0 + row) * QKVW + 2048 + h * 128) * 2 + gs * 16;
        load_lds16(src, Ks + i * 1024);
      }
    } else {
      #pragma unroll
      for (int i = 0; i < 16; ++i) {
        int e = i * 64 + l;
        int row = e >> 3, g = e & 7;
        int gs = g ^ (row & 7);
        const char* src = (const char*)VT +
            ((size_t)(bh * 128 + row) * 1024 + k0) * 2 + gs * 16;
        load_lds16(src, VTs + i * 1024);
      }
    }
    __syncthreads();

    // S^T = K x Q^T (log2 domain after SCL)
    f32x16 sT[2];
    #pragma unroll
    for (int kk = 0; kk < 2; ++kk) {
      #pragma unroll
      for (int r = 0; r < 16; ++r) sT[kk][r] = 0.f;
      #pragma unroll
      for (int c = 0; c < 8; ++c) {
        bf16x8 kf = *(const bf16x8*)(Ks + (kk * 32 + lo) * 256 + (((2 * c + hv) ^ (lo & 7)) * 16));
        sT[kk] = __builtin_amdgcn_mfma_f32_32x32x16_bf16(kf, qf[c], sT[kk], 0, 0, 0);
      }
    }
    bool diag = (kt == qt);
    float pv[2][16];
    #pragma unroll
    for (int kk = 0; kk < 2; ++kk)
      #pragma unroll
      for (int r = 0; r < 16; ++r) {
        float v = sT[kk][r] * SCL;
        if (diag) {
          int kg = k0 + kk * 32 + (r & 3) + 8 * (r >> 2) + 4 * hv;
          if (kg > qrow) v = -1e30f;
        }
        pv[kk][r] = v;
      }
    float mx = pv[0][0];
    #pragma unroll
    for (int kk = 0; kk < 2; ++kk)
      #pragma unroll
      for (int r = 0; r < 16; ++r) mx = fmaxf(mx, pv[kk][r]);
    mx = fmaxf(mx, __shfl_xor(mx, 32, 64));
    // defer-max (T13): skip O-rescale when max growth <= 8 (P bounded by 2^8)
    if (!__all(mx <= mrun + 8.f)) {
      float mnew = fmaxf(mrun, mx);
      float fac = exp2f(mrun - mnew);
      lrun *= fac;
      #pragma unroll
      for (int n = 0; n < 4; ++n)
        #pragma unroll
        for (int r = 0; r < 16; ++r) o[n][r] *= fac;
      mrun = mnew;
    }
    float rs = 0.f;
    #pragma unroll
    for (int kk = 0; kk < 2; ++kk)
      #pragma unroll
      for (int r = 0; r < 16; ++r) {
        float p = exp2f(pv[kk][r] - mrun);
        pv[kk][r] = p;
        rs += p;
      }
    rs += __shfl_xor(rs, 32, 64);
    lrun += rs;

    unsigned pk[2][4][2];
    #pragma unroll
    for (int kk = 0; kk < 2; ++kk)
      #pragma unroll
      for (int m = 0; m < 4; ++m)
        #pragma unroll
        for (int u = 0; u < 2; ++u)
          pk[kk][m][u] = pack2(pv[kk][m * 4 + 2 * u], pv[kk][m * 4 + 2 * u + 1]);

    #pragma unroll
    for (int kk = 0; kk < 2; ++kk) {
      #pragma unroll
      for (int s = 0; s < 2; ++s) {
        unsigned a0 = __shfl(pk[kk][2 * s][0], src0, 64);
        unsigned b0 = __shfl(pk[kk][2 * s + 1][0], src0, 64);
        unsigned a1 = __shfl(pk[kk][2 * s][1], src0, 64);
        unsigned b1 = __shfl(pk[kk][2 * s + 1][1], src0, 64);
        unsigned a2 = __shfl(pk[kk][2 * s][0], src1, 64);
        unsigned b2 = __shfl(pk[kk][2 * s + 1][0], src1, 64);
        unsigned a3 = __shfl(pk[kk][2 * s][1], src1, 64);
        unsigned b3 = __shfl(pk[kk][2 * s + 1][1], src1, 64);
        union { unsigned u[4]; bf16x8 v; } pb;
        pb.u[0] = hv ? b0 : a0;
        pb.u[1] = hv ? b1 : a1;
        pb.u[2] = hv ? b2 : a2;
        pb.u[3] = hv ? b3 : a3;
        int ks16 = 2 * kk + s;
        #pragma unroll
        for (int n = 0; n < 4; ++n) {
          bf16x8 vf = *(const bf16x8*)(VTs + (n * 32 + lo) * 128 +
                                       (((2 * ks16 + hv) ^ (lo & 7)) * 16));
          o[n] = __builtin_amdgcn_mfma_f32_32x32x16_bf16(vf, pb.v, o[n], 0, 0, 0);
        }
      }
    }
  }
  float inv = 1.f / lrun;
  __bf16* op = QKV + (size_t)(b * 1024 + qrow) * QKVW + h * 128;
  #pragma unroll
  for (int n = 0; n < 4; ++n)
    #pragma unroll
    for (int m4 = 0; m4 < 4; ++m4) {
      bf16x4 ov;
      #pragma unroll
      for (int j = 0; j < 4; ++j) ov[j] = (__bf16)(o[n][m4 * 4 + j] * inv);
      *(bf16x4*)(op + n * 32 + 8 * m4 + 4 * hv) = ov;
    }
}

extern "C" void kernel_launch(void* const* d_in, const int* in_sizes, int n_in,
                              void* d_out, int out_size, void* d_ws, size_t ws_size,
                              hipStream_t stream) {
  const float* x    = (const float*)d_in[0];
  const float* fc   = (const float*)d_in[1];
  const float* fs   = (const float*)d_in[2];
  const float* wq   = (const float*)d_in[3];
  const float* wk   = (const float*)d_in[4];
  const float* wv   = (const float*)d_in[5];
  const float* wo   = (const float*)d_in[6];
  const float* wm   = (const float*)d_in[7];
  const float* beta = (const float*)d_in[8];

  char* wsb = (char*)d_ws;
  __bf16* xb    = (__bf16*)(wsb);                    // 16MB (reused: MTmix)
  __bf16* MTqkv = (__bf16*)(wsb + 16777216L);        // 24MB (reused: MTwo)
  __bf16* QKV   = (__bf16*)(wsb + 41943040L);        // 48MB
  __bf16* VTb   = (__bf16*)(wsb + 92274688L);        // 16MB (reused: Ymix)
  double* s8    = (double*)(wsb + 109051904L);       // 32 doubles
  __bf16* MTmix = xb;
  __bf16* MTwo  = MTqkv;
  __bf16* Ymix  = VTb;

  dim3 blk(256);

  cast_x<<<8192, blk, 0, stream>>>(x, xb);
  scale4_kernel<<<32, blk, 0, stream>>>(wq, wk, wv, wo, s8);
  build_oct3<<<dim3(16384, 3), blk, 0, stream>>>(wq, wk, wv, s8, MTqkv);

  // QKV = xb @ [Mq|Mk|Mv]^T (phase-split counted-vmcnt GEMM)
  gemm_qkv<<<512, dim3(512), 0, stream>>>(xb, MTqkv, QKV);

  rope_bf16<<<4096, blk, 0, stream>>>(QKV, fc, fs);
  transpose_v<<<dim3(16, 64), blk, 0, stream>>>(QKV, VTb);

  attn_mfma2<<<dim3(16, 64), dim3(128), 0, stream>>>(QKV, VTb);

  build_mix_T<<<4096, blk, 0, stream>>>(wm, beta, MTmix);
  gemm_bf16<1><<<dim3(8, 32, 2), blk, 0, stream>>>(QKV, QKVW, MTmix, 1024, Ymix, 2048, 1024, 1024, 1024);

  build_oct_T<<<16384, blk, 0, stream>>>(wo, s8 + 24, MTwo);
  gemm_bf16<0><<<dim3(16, 32, 1), blk, 0, stream>>>(Ymix, 2048, MTwo, 2048, (float*)d_out, 2048, 2048, 0, 0);
}

// Round 5
// 430.023 us; speedup vs baseline: 9.2990x; 1.0692x over previous
//
#include <hip/hip_runtime.h>
#include <math.h>

#define CDIM 2048
#define QKVW 6144

typedef __bf16 bf16x8 __attribute__((ext_vector_type(8)));
typedef __bf16 bf16x4 __attribute__((ext_vector_type(4)));
typedef float  f32x4  __attribute__((ext_vector_type(4)));
typedef float  f32x16 __attribute__((ext_vector_type(16)));

__device__ __constant__ float SIGNS_c[64] = {
  1,  1,  1,  1,  1,  1,  1,  1,
  1, -1,  1, -1,  1, -1, -1,  1,
  1, -1, -1,  1,  1,  1, -1, -1,
  1,  1, -1, -1,  1, -1,  1, -1,
  1, -1, -1, -1, -1,  1,  1,  1,
  1,  1, -1,  1, -1, -1, -1,  1,
  1,  1,  1, -1, -1,  1, -1, -1,
  1, -1,  1,  1, -1, -1,  1, -1
};

__device__ __forceinline__ void load_lds16(const void* g, void* lp) {
  __builtin_amdgcn_global_load_lds(
      (const __attribute__((address_space(1))) unsigned int*)g,
      (__attribute__((address_space(3))) unsigned int*)lp, 16, 0, 0);
}

__device__ __forceinline__ void wg_barrier() {
  asm volatile("" ::: "memory");
  __builtin_amdgcn_s_barrier();
  asm volatile("" ::: "memory");
}

__device__ __forceinline__ unsigned pack2(float a, float b) {
  union { __bf16 h[2]; unsigned u; } x;
  x.h[0] = (__bf16)a; x.h[1] = (__bf16)b; return x.u;
}

// ---- mean(|W|) in f64 for all 4 weight tensors ----
__global__ void scale4_kernel(const float* __restrict__ wq, const float* __restrict__ wk,
                              const float* __restrict__ wv, const float* __restrict__ wo,
                              double* __restrict__ s8) {
  int which = blockIdx.x >> 3, m = blockIdx.x & 7;
  const float* W = (which == 0) ? wq : (which == 1) ? wk : (which == 2) ? wv : wo;
  const float* w = W + (m << 16);
  double acc = 0.0;
  for (int i = threadIdx.x; i < 65536; i += 256) acc += (double)fabsf(w[i]);
  __shared__ double red[256];
  red[threadIdx.x] = acc;
  __syncthreads();
  for (int s = 128; s > 0; s >>= 1) {
    if (threadIdx.x < s) red[threadIdx.x] += red[threadIdx.x + s];
    __syncthreads();
  }
  if (threadIdx.x == 0) s8[which * 8 + m] = red[0] / 65536.0 + 1e-8;
}

__global__ void build_oct3(const float* __restrict__ wq, const float* __restrict__ wk,
                           const float* __restrict__ wv, const double* __restrict__ s8,
                           __bf16* __restrict__ MT) {
  int z = blockIdx.y;
  const float* W = (z == 0) ? wq : (z == 1) ? wk : wv;
  const double* sp = s8 + z * 8;
  __bf16* out = MT + (size_t)z * 4194304;
  int idx = blockIdx.x * 256 + threadIdx.x;
  int row = idx & 2047, col = idx >> 11;
  int i = col >> 8, d = col & 255, j = row >> 8, c = row & 255;
  int m = i ^ j;
  double s = sp[m];
  double q = rint((double)W[(m << 16) + (c << 8) + d] / s);
  q = fmin(fmax(q, -1.0), 1.0);
  out[idx] = (__bf16)(SIGNS_c[i * 8 + j] * (float)(q * s));
}

__global__ void build_oct_T(const float* __restrict__ W, const double* __restrict__ s8,
                            __bf16* __restrict__ MT) {
  int idx = blockIdx.x * 256 + threadIdx.x;
  int row = idx & 2047, col = idx >> 11;
  int i = col >> 8, d = col & 255, j = row >> 8, c = row & 255;
  int m = i ^ j;
  double s = s8[m];
  double q = rint((double)W[(m << 16) + (c << 8) + d] / s);
  q = fmin(fmax(q, -1.0), 1.0);
  MT[idx] = (__bf16)(SIGNS_c[i * 8 + j] * (float)(q * s));
}

__global__ void build_mix_T(const float* __restrict__ Wm, const float* __restrict__ beta,
                            __bf16* __restrict__ MT) {
  int idx = blockIdx.x * 256 + threadIdx.x;
  int row = idx & 1023, col = idx >> 10;
  int j = row >> 7, dd = row & 127;
  int i = col >> 7, e = col & 127;
  MT[idx] = (__bf16)(SIGNS_c[i * 8 + j] * Wm[((i ^ j) << 14) + (dd << 7) + e] * beta[e]);
}

__global__ void cast_x(const float* __restrict__ x, __bf16* __restrict__ xb) {
  int i = blockIdx.x * 256 + threadIdx.x;
  float4 v = *(const float4*)(x + (size_t)i * 4);
  bf16x4 o;
  o[0] = (__bf16)v.x; o[1] = (__bf16)v.y; o[2] = (__bf16)v.z; o[3] = (__bf16)v.w;
  *(bf16x4*)(xb + (size_t)i * 4) = o;
}

// ---- phase-split counted-vmcnt GEMM, BM=256, BK=32, 8 waves, dbuf, chunked XCD swizzle ----
// C[z][Mx(NBX*BN)] = A[z][Mx KLEN] @ BT^T ; BT row-major [N][KLEN].
template<int BN, int NBY, int NBX, int CBY, int CBX, int KLEN, int LDA, int OUT_BF16>
__global__ __launch_bounds__(512, 2)
void gemm_ps(const __bf16* __restrict__ A, const __bf16* __restrict__ BT,
             void* __restrict__ Cout, int az, int cz, int ldc) {
  constexpr int FN = BN / 64;              // b-frags per wave (3 or 2)
  constexpr int LB = (BN > 128) ? 2 : 1;   // B staging loads per thread
  constexpr int VC = 2 + LB;               // counted vmcnt (one stage in flight)
  constexpr int BUFSZ = 16384 + 8192 * LB;
  constexpr int CGX = NBX / CBX;
  static_assert((NBY / CBY) * CGX == 8, "chunk grid must be 8 XCDs");
  __shared__ __align__(16) char smem[2 * BUFSZ];
  int tid = threadIdx.x;
  int w = tid >> 6, l = tid & 63, hi = l >> 4, lo = l & 15;
  int wm = w >> 2, wn = w & 3;
  // chunked XCD swizzle: each XCD owns a CBYxCBX block rectangle
  int lin = blockIdx.x;
  int xcd = lin & 7, idx = lin >> 3;
  int cy = xcd / CGX, cx = xcd % CGX;
  int iby = idx / CBX, ibx = idx % CBX;
  int bm = (cy * CBY + iby) * 256;
  int bn = (cx * CBX + ibx) * BN;
  const char* Ab = (const char*)(A + (size_t)blockIdx.y * az) + (size_t)bm * LDA * 2;
  const char* Bb = (const char*)BT + (size_t)bn * KLEN * 2;

  // swizzled frag read base: lds-row = row>>1 (128B rows), slot = ((row&1)*4+hi)^(lds-row&7)
  int sw = (((lo & 1) << 2) + hi) ^ (lo >> 1);
  int base_a = (wm * 64 + (lo >> 1)) * 128 + sw * 16;
  int base_b = 16384 + (wn * (BN / 8) + (lo >> 1)) * 128 + sw * 16;

  // staging inverse map: lds granule e=(lr,sl) holds logical (row=lr*2+(x>>2), g=x&3), x=sl^(lr&7)
  int se_r[2], se_g[2];
  #pragma unroll
  for (int q = 0; q < 2; ++q) {
    int e = q * 512 + tid;
    int lr = e >> 3, sl = e & 7;
    int x = sl ^ (lr & 7);
    se_r[q] = lr * 2 + (x >> 2);
    se_g[q] = x & 3;
  }
  int dstoff[2] = { (0 * 512 + w * 64) * 16, (1 * 512 + w * 64) * 16 };

  f32x4 acc[8][FN];
  #pragma unroll
  for (int m = 0; m < 8; ++m)
    #pragma unroll
    for (int n = 0; n < FN; ++n) acc[m][n] = (f32x4){0.f, 0.f, 0.f, 0.f};

  #define STAGE(BUFI, K0) do {                                                   \
    char* As_ = smem + (BUFI) * BUFSZ;                                           \
    char* Bs_ = As_ + 16384;                                                     \
    _Pragma("unroll")                                                            \
    for (int q = 0; q < 2; ++q)                                                  \
      load_lds16(Ab + (size_t)se_r[q] * (LDA * 2) + (size_t)(K0) * 2 + se_g[q] * 16, \
                 As_ + dstoff[q]);                                               \
    _Pragma("unroll")                                                            \
    for (int q = 0; q < LB; ++q)                                                 \
      load_lds16(Bb + (size_t)se_r[q] * (KLEN * 2) + (size_t)(K0) * 2 + se_g[q] * 16, \
                 Bs_ + dstoff[q]);                                               \
  } while (0)

  #define WAITVC() do {                                                \
    if constexpr (VC == 4) asm volatile("s_waitcnt vmcnt(4)" ::: "memory"); \
    else                   asm volatile("s_waitcnt vmcnt(3)" ::: "memory"); \
  } while (0)

  constexpr int NT = KLEN / 32;
  STAGE(0, 0);
  STAGE(1, 32);
  WAITVC();
  wg_barrier();

  for (int t = 0; t < NT; ++t) {
    char* buf = smem + (t & 1) * BUFSZ;
    bf16x8 bfr[FN], afr[8];
    #pragma unroll
    for (int n = 0; n < FN; ++n) bfr[n] = *(const bf16x8*)(buf + base_b + n * 1024);
    #pragma unroll
    for (int m = 0; m < 8; ++m) afr[m] = *(const bf16x8*)(buf + base_a + m * 1024);
    __builtin_amdgcn_s_setprio(1);
    #pragma unroll
    for (int m = 0; m < 4; ++m)
      #pragma unroll
      for (int n = 0; n < FN; ++n)
        acc[m][n] = __builtin_amdgcn_mfma_f32_16x16x32_bf16(afr[m], bfr[n], acc[m][n], 0, 0, 0);
    __builtin_amdgcn_s_setprio(0);
    asm volatile("s_waitcnt lgkmcnt(0)" ::: "memory");  // all frag reads of buf done
    wg_barrier();

    if (t + 2 < NT) STAGE(t & 1, (t + 2) * 32);
    __builtin_amdgcn_s_setprio(1);
    #pragma unroll
    for (int m = 4; m < 8; ++m)
      #pragma unroll
      for (int n = 0; n < FN; ++n)
        acc[m][n] = __builtin_amdgcn_mfma_f32_16x16x32_bf16(afr[m], bfr[n], acc[m][n], 0, 0, 0);
    __builtin_amdgcn_s_setprio(0);
    if (t + 2 < NT) { WAITVC(); }
    else            { asm volatile("s_waitcnt vmcnt(0)" ::: "memory"); }
    wg_barrier();
  }
  #undef STAGE
  #undef WAITVC

  #pragma unroll
  for (int m = 0; m < 8; ++m)
    #pragma unroll
    for (int n = 0; n < FN; ++n)
      #pragma unroll
      for (int r = 0; r < 4; ++r) {
        int row = bm + wm * 128 + m * 16 + hi * 4 + r;
        int col = bn + wn * (BN / 4) + n * 16 + lo;
        if (OUT_BF16)
          ((__bf16*)Cout)[(size_t)blockIdx.y * cz + (size_t)row * ldc + col] = (__bf16)acc[m][n][r];
        else
          ((float*)Cout)[(size_t)blockIdx.y * cz + (size_t)row * ldc + col] = acc[m][n][r];
      }
}

// ---- RoPE on Q,K columns of QKV ----
__global__ void rope_bf16(__bf16* __restrict__ QKV,
                          const float* __restrict__ fc, const float* __restrict__ fs) {
  int idx = blockIdx.x * 256 + threadIdx.x;
  int pg = idx & 15;
  int h = (idx >> 4) & 15;
  int n = idx >> 8;
  int t = n & 1023;
  float4 c4 = *(const float4*)(fc + t * 64 + pg * 4);
  float4 s4 = *(const float4*)(fs + t * 64 + pg * 4);
  float c[4] = {c4.x, c4.y, c4.z, c4.w};
  float s[4] = {s4.x, s4.y, s4.z, s4.w};
  size_t ofs = (size_t)n * QKVW + h * 128 + pg * 8;
  bf16x8 q = *(bf16x8*)(QKV + ofs);
  bf16x8 k = *(bf16x8*)(QKV + 2048 + ofs);
  bf16x8 oq, ok;
  #pragma unroll
  for (int j = 0; j < 4; ++j) {
    float x = (float)q[2 * j], y = (float)q[2 * j + 1];
    oq[2 * j]     = (__bf16)(x * c[j] - y * s[j]);
    oq[2 * j + 1] = (__bf16)(x * s[j] + y * c[j]);
    float u = (float)k[2 * j], vv = (float)k[2 * j + 1];
    ok[2 * j]     = (__bf16)(u * c[j] - vv * s[j]);
    ok[2 * j + 1] = (__bf16)(u * s[j] + vv * c[j]);
  }
  *(bf16x8*)(QKV + ofs) = oq;
  *(bf16x8*)(QKV + 2048 + ofs) = ok;
}

// ---- transpose V cols of QKV -> VT[(bh*128+d)][t] ----
__global__ __launch_bounds__(256)
void transpose_v(const __bf16* __restrict__ QKV, __bf16* __restrict__ VT) {
  __shared__ __bf16 tile[64][136];
  int tid = threadIdx.x;
  int tt = blockIdx.x;
  int bh = blockIdx.y;
  int b = bh >> 4, h = bh & 15;
  int t0 = tt * 64;
  #pragma unroll
  for (int q = 0; q < 4; ++q) {
    int i = q * 256 + tid;
    int tr = i >> 4, u = i & 15;
    bf16x8 v = *(const bf16x8*)(QKV + (size_t)(b * 1024 + t0 + tr) * QKVW + 4096 + h * 128 + u * 8);
    *(bf16x8*)&tile[tr][u * 8] = v;
  }
  __syncthreads();
  #pragma unroll
  for (int q = 0; q < 4; ++q) {
    int i = q * 256 + tid;
    int d = i >> 3, tu = i & 7;
    bf16x8 o;
    #pragma unroll
    for (int jj = 0; jj < 8; ++jj) o[jj] = tile[tu * 8 + jj][d];
    *(bf16x8*)(VT + ((size_t)bh * 128 + d) * 1024 + t0 + tu * 8) = o;
  }
}

// ---- 32x32 MFMA flash attention, causal, swapped operands, exp2, QBLK=128, 4 waves ----
__global__ __launch_bounds__(256)
void attn_mfma2(__bf16* __restrict__ QKV, const __bf16* __restrict__ VT) {
  __shared__ __align__(16) char smem[32768];
  char* Ks  = smem;          // [64][128] bf16, swizzled granules
  char* VTs = smem + 16384;  // [128][64] bf16, swizzled granules
  int tid = threadIdx.x;
  int w = tid >> 6, l = tid & 63;
  int lo = l & 31, hv = l >> 5;
  int qt = 7 - (int)blockIdx.x;              // reversed for tail packing
  int bh = blockIdx.y, b = bh >> 4, h = bh & 15;
  int qb = qt * 128;
  int wq0 = qb + w * 32;
  int qrow = wq0 + lo;
  const __bf16* qp = QKV + (size_t)(b * 1024 + qrow) * QKVW + h * 128;
  bf16x8 qf[8];
  #pragma unroll
  for (int c = 0; c < 8; ++c) qf[c] = *(const bf16x8*)(qp + c * 16 + hv * 8);

  f32x16 o[4];
  #pragma unroll
  for (int n = 0; n < 4; ++n)
    #pragma unroll
    for (int r = 0; r < 16; ++r) o[n][r] = 0.f;
  float mrun = -1e30f, lrun = 0.f;
  const float SCL = 0.08838834764831845f * 1.4426950408889634f;  // scale * log2(e)
  int src0 = lo, src1 = 32 + lo;
  int nt = 2 * qt + 2;

  for (int kt = 0; kt < nt; ++kt) {
    int k0 = kt * 64;
    __syncthreads();
    // all 4 waves stage: K tile 1024 granules, V tile 1024 granules
    #pragma unroll
    for (int i = 0; i < 4; ++i) {
      int e = i * 256 + tid;
      int row = e >> 4, g = e & 15;
      int gs = g ^ (row & 7);
      const char* src = (const char*)QKV +
          ((size_t)(b * 1024 + k0 + row) * QKVW + 2048 + h * 128) * 2 + gs * 16;
      load_lds16(src, Ks + (i * 256 + w * 64) * 16);
    }
    #pragma unroll
    for (int i = 0; i < 4; ++i) {
      int e = i * 256 + tid;
      int row = e >> 3, g = e & 7;
      int gs = g ^ (row & 7);
      const char* src = (const char*)VT +
          ((size_t)(bh * 128 + row) * 1024 + k0) * 2 + gs * 16;
      load_lds16(src, VTs + (i * 256 + w * 64) * 16);
    }
    __syncthreads();

    if (k0 > wq0 + 31) continue;   // tile fully masked for this wave

    // S^T = K x Q^T (log2 domain after SCL)
    f32x16 sT[2];
    #pragma unroll
    for (int kk = 0; kk < 2; ++kk) {
      #pragma unroll
      for (int r = 0; r < 16; ++r) sT[kk][r] = 0.f;
      #pragma unroll
      for (int c = 0; c < 8; ++c) {
        bf16x8 kf = *(const bf16x8*)(Ks + (kk * 32 + lo) * 256 + (((2 * c + hv) ^ (lo & 7)) * 16));
        sT[kk] = __builtin_amdgcn_mfma_f32_32x32x16_bf16(kf, qf[c], sT[kk], 0, 0, 0);
      }
    }
    bool diag = (k0 + 63 > wq0);
    float pv[2][16];
    #pragma unroll
    for (int kk = 0; kk < 2; ++kk)
      #pragma unroll
      for (int r = 0; r < 16; ++r) {
        float v = sT[kk][r] * SCL;
        if (diag) {
          int kg = k0 + kk * 32 + (r & 3) + 8 * (r >> 2) + 4 * hv;
          if (kg > qrow) v = -1e30f;
        }
        pv[kk][r] = v;
      }
    float mx = pv[0][0];
    #pragma unroll
    for (int kk = 0; kk < 2; ++kk)
      #pragma unroll
      for (int r = 0; r < 16; ++r) mx = fmaxf(mx, pv[kk][r]);
    mx = fmaxf(mx, __shfl_xor(mx, 32, 64));
    if (!__all(mx <= mrun + 8.f)) {        // defer-max (T13)
      float mnew = fmaxf(mrun, mx);
      float fac = exp2f(mrun - mnew);
      lrun *= fac;
      #pragma unroll
      for (int n = 0; n < 4; ++n)
        #pragma unroll
        for (int r = 0; r < 16; ++r) o[n][r] *= fac;
      mrun = mnew;
    }
    float rs = 0.f;
    #pragma unroll
    for (int kk = 0; kk < 2; ++kk)
      #pragma unroll
      for (int r = 0; r < 16; ++r) {
        float p = exp2f(pv[kk][r] - mrun);
        pv[kk][r] = p;
        rs += p;
      }
    rs += __shfl_xor(rs, 32, 64);
    lrun += rs;

    unsigned pk[2][4][2];
    #pragma unroll
    for (int kk = 0; kk < 2; ++kk)
      #pragma unroll
      for (int m = 0; m < 4; ++m)
        #pragma unroll
        for (int u = 0; u < 2; ++u)
          pk[kk][m][u] = pack2(pv[kk][m * 4 + 2 * u], pv[kk][m * 4 + 2 * u + 1]);

    #pragma unroll
    for (int kk = 0; kk < 2; ++kk) {
      #pragma unroll
      for (int s = 0; s < 2; ++s) {
        unsigned a0 = __shfl(pk[kk][2 * s][0], src0, 64);
        unsigned b0 = __shfl(pk[kk][2 * s + 1][0], src0, 64);
        unsigned a1 = __shfl(pk[kk][2 * s][1], src0, 64);
        unsigned b1 = __shfl(pk[kk][2 * s + 1][1], src0, 64);
        unsigned a2 = __shfl(pk[kk][2 * s][0], src1, 64);
        unsigned b2 = __shfl(pk[kk][2 * s + 1][0], src1, 64);
        unsigned a3 = __shfl(pk[kk][2 * s][1], src1, 64);
        unsigned b3 = __shfl(pk[kk][2 * s + 1][1], src1, 64);
        union { unsigned u[4]; bf16x8 v; } pb;
        pb.u[0] = hv ? b0 : a0;
        pb.u[1] = hv ? b1 : a1;
        pb.u[2] = hv ? b2 : a2;
        pb.u[3] = hv ? b3 : a3;
        int ks16 = 2 * kk + s;
        #pragma unroll
        for (int n = 0; n < 4; ++n) {
          bf16x8 vf = *(const bf16x8*)(VTs + (n * 32 + lo) * 128 +
                                       (((2 * ks16 + hv) ^ (lo & 7)) * 16));
          o[n] = __builtin_amdgcn_mfma_f32_32x32x16_bf16(vf, pb.v, o[n], 0, 0, 0);
        }
      }
    }
  }
  float inv = 1.f / lrun;
  __bf16* op = QKV + (size_t)(b * 1024 + qrow) * QKVW + h * 128;
  #pragma unroll
  for (int n = 0; n < 4; ++n)
    #pragma unroll
    for (int m4 = 0; m4 < 4; ++m4) {
      bf16x4 ov;
      #pragma unroll
      for (int j = 0; j < 4; ++j) ov[j] = (__bf16)(o[n][m4 * 4 + j] * inv);
      *(bf16x4*)(op + n * 32 + 8 * m4 + 4 * hv) = ov;
    }
}

extern "C" void kernel_launch(void* const* d_in, const int* in_sizes, int n_in,
                              void* d_out, int out_size, void* d_ws, size_t ws_size,
                              hipStream_t stream) {
  const float* x    = (const float*)d_in[0];
  const float* fc   = (const float*)d_in[1];
  const float* fs   = (const float*)d_in[2];
  const float* wq   = (const float*)d_in[3];
  const float* wk   = (const float*)d_in[4];
  const float* wv   = (const float*)d_in[5];
  const float* wo   = (const float*)d_in[6];
  const float* wm   = (const float*)d_in[7];
  const float* beta = (const float*)d_in[8];

  char* wsb = (char*)d_ws;
  __bf16* xb    = (__bf16*)(wsb);                    // 16MB (reused: MTmix)
  __bf16* MTqkv = (__bf16*)(wsb + 16777216L);        // 24MB (reused: MTwo)
  __bf16* QKV   = (__bf16*)(wsb + 41943040L);        // 48MB
  __bf16* VTb   = (__bf16*)(wsb + 92274688L);        // 16MB (reused: Ymix)
  double* s8    = (double*)(wsb + 109051904L);       // 32 doubles
  __bf16* MTmix = xb;
  __bf16* MTwo  = MTqkv;
  __bf16* Ymix  = VTb;

  dim3 blk(256);

  cast_x<<<8192, blk, 0, stream>>>(x, xb);
  scale4_kernel<<<32, blk, 0, stream>>>(wq, wk, wv, wo, s8);
  build_oct3<<<dim3(16384, 3), blk, 0, stream>>>(wq, wk, wv, s8, MTqkv);

  // QKV = xb @ [Mq|Mk|Mv]^T   (16x32 grid of 256x192, 8x8 XCD chunks)
  gemm_ps<192, 16, 32, 8, 8, 2048, 2048, 1>
      <<<dim3(512, 1), dim3(512), 0, stream>>>(xb, MTqkv, QKV, 0, 0, QKVW);

  rope_bf16<<<4096, blk, 0, stream>>>(QKV, fc, fs);
  transpose_v<<<dim3(16, 64), blk, 0, stream>>>(QKV, VTb);

  attn_mfma2<<<dim3(8, 64), blk, 0, stream>>>(QKV, VTb);

  // mixer: block-diagonal, batched over 2 groups (z); A = attn output in Q cols of QKV
  build_mix_T<<<4096, blk, 0, stream>>>(wm, beta, MTmix);
  gemm_ps<128, 16, 8, 4, 4, 1024, 6144, 1>
      <<<dim3(128, 2), dim3(512), 0, stream>>>(QKV, MTmix, Ymix, 1024, 1024, 2048);

  build_oct_T<<<16384, blk, 0, stream>>>(wo, s8 + 24, MTwo);
  gemm_ps<128, 16, 16, 4, 8, 2048, 2048, 0>
      <<<dim3(256, 1), dim3(512), 0, stream>>>(Ymix, MTwo, (float*)d_out, 0, 0, 2048);
}